// Round 4
// baseline (191.239 us; speedup 1.0000x reference)
//
#include <hip/hip_runtime.h>
#include <hip/hip_bf16.h>

typedef unsigned short u16;
typedef __bf16 bf16x8 __attribute__((ext_vector_type(8)));
typedef float f32x4 __attribute__((ext_vector_type(4)));
typedef float f32x16 __attribute__((ext_vector_type(16)));
typedef unsigned u32x4 __attribute__((ext_vector_type(4)));

// B=2, T=2048, C=1024, H=16, hd=64. scale = 1/32; log2(e)/32 folded into Q.
#define QSCALE 0.045084220027780106f

__device__ __forceinline__ u16 f2b(float f) {
  unsigned x = __float_as_uint(f);
  unsigned r = (x + 0x7fffu + ((x >> 16) & 1u)) >> 16;  // RNE
  return (u16)r;
}

__device__ __forceinline__ void gll16(const void* g, void* l) {
  __builtin_amdgcn_global_load_lds((const __attribute__((address_space(1))) void*)g,
                                   (__attribute__((address_space(3))) void*)l, 16, 0, 0);
}

__device__ __forceinline__ f32x4 mfma16(bf16x8 a, bf16x8 b, f32x4 c) {
  return __builtin_amdgcn_mfma_f32_16x16x32_bf16(a, b, c, 0, 0, 0);
}
__device__ __forceinline__ f32x16 mfma32(bf16x8 a, bf16x8 b, f32x16 c) {
  return __builtin_amdgcn_mfma_f32_32x32x16_bf16(a, b, c, 0, 0, 0);
}

// v_permlane32_swap_b32 a,b : a' = {a_lo, b_lo}, b' = {a_hi, b_hi}
// ONLY safe with operands holding distinct values (identical values may be
// register-coalesced -> v_permlane32_swap_b32 v, v == half-swap, wrong).
__device__ __forceinline__ void plswap(unsigned& a, unsigned& b) {
  asm volatile("v_permlane32_swap_b32 %0, %1" : "+v"(a), "+v"(b));
}
__device__ __forceinline__ unsigned cvtpk(float lo, float hi) {
  unsigned r;
  asm("v_cvt_pk_bf16_f32 %0, %1, %2" : "=v"(r) : "v"(lo), "v"(hi));
  return r;
}

// ---------------- fp32 -> bf16 convert (all three tensors, one launch) ----------------
__global__ __launch_bounds__(256) void cvt3(const float* __restrict__ x,
                                            const float* __restrict__ wa,
                                            const float* __restrict__ wp,
                                            u16* __restrict__ dx,
                                            u16* __restrict__ dwa,
                                            u16* __restrict__ dwp) {
  const int N1 = 4194304, N2 = 3145728;
  int i = (blockIdx.x * 256 + threadIdx.x) * 4;
  const float* s;
  u16* d;
  int off;
  if (i < N1) { s = x; d = dx; off = i; }
  else if (i < N1 + N2) { s = wa; d = dwa; off = i - N1; }
  else { s = wp; d = dwp; off = i - N1 - N2; }
  float4 v = *(const float4*)(s + off);
  ushort4 o;
  o.x = f2b(v.x); o.y = f2b(v.y); o.z = f2b(v.z); o.w = f2b(v.w);
  *(ushort4*)(d + off) = o;
}

// ---------------- GEMM1: qkv = x @ w_attn^T + b_attn, scatter to Q/K/Vt ----------------
__global__ __launch_bounds__(256) void gemm_qkv(const u16* __restrict__ A,
                                                const u16* __restrict__ W,
                                                const float* __restrict__ bias,
                                                u16* __restrict__ Qb,
                                                u16* __restrict__ Kb,
                                                u16* __restrict__ Vtb) {
  __shared__ u16 As[128 * 64];
  __shared__ u16 Bs[128 * 64];
  const int K = 1024;
  int bn = blockIdx.x, bm = blockIdx.y;
  int tid = threadIdx.x, lane = tid & 63, w = tid >> 6;
  int wm = w >> 1, wn = w & 1, g = lane >> 4, c = lane & 15;
  f32x4 acc[4][4] = {};
  const u16* Arow = A + (size_t)(bm * 128) * K;
  const u16* Wrow = W + (size_t)(bn * 128) * K;
  for (int k0 = 0; k0 < K; k0 += 64) {
#pragma unroll
    for (int rr = 0; rr < 4; ++rr) {
      int ci = rr * 256 + tid;
      gll16(Arow + (ci >> 3) * K + k0 + (ci & 7) * 8, As + ci * 8);
    }
#pragma unroll
    for (int rr = 0; rr < 4; ++rr) {
      int ci = rr * 256 + tid;
      gll16(Wrow + (ci >> 3) * K + k0 + (ci & 7) * 8, Bs + ci * 8);
    }
    __syncthreads();
#pragma unroll
    for (int kk = 0; kk < 2; ++kk) {
      int koff = kk * 32 + g * 8;
      bf16x8 af[4], bfr[4];
#pragma unroll
      for (int mi = 0; mi < 4; ++mi)
        af[mi] = *(const bf16x8*)&As[(wm * 64 + mi * 16 + c) * 64 + koff];
#pragma unroll
      for (int ni = 0; ni < 4; ++ni)
        bfr[ni] = *(const bf16x8*)&Bs[(wn * 64 + ni * 16 + c) * 64 + koff];
#pragma unroll
      for (int mi = 0; mi < 4; ++mi)
#pragma unroll
        for (int ni = 0; ni < 4; ++ni)
          acc[mi][ni] = mfma16(af[mi], bfr[ni], acc[mi][ni]);
    }
    __syncthreads();
  }
#pragma unroll
  for (int mi = 0; mi < 4; ++mi)
#pragma unroll
    for (int ni = 0; ni < 4; ++ni)
#pragma unroll
      for (int r = 0; r < 4; ++r) {
        int row = bm * 128 + wm * 64 + mi * 16 + g * 4 + r;
        int col = bn * 128 + wn * 64 + ni * 16 + c;
        float v = acc[mi][ni][r] + bias[col];
        int b = row >> 11, t = row & 2047;
        int h = col / 192, j = col - h * 192;
        int bh = b * 16 + h;
        if (j < 64) {
          Qb[((size_t)bh * 2048 + t) * 64 + j] = f2b(v * QSCALE);
        } else if (j < 128) {
          Kb[((size_t)bh * 2048 + t) * 64 + (j - 64)] = f2b(v);
        } else {
          Vtb[((size_t)bh * 64 + (j - 128)) * 2048 + t] = f2b(v);
        }
      }
}

// ---------------- Flash attention, 32x32 swapped-QK^T, in-register softmax ----------------
// grid: (T/64, B*H). 2 waves/block; wave wv owns q rows [wv*32, wv*32+32).
// Per lane: q = lane&31 (c5), h = lane>>5. S^T = mfma32(K, Q): lane holds
// S[k=(reg&3)+8*(reg>>2)+4h][q=c5] for its h-half of each 32-k block.
__global__ __launch_bounds__(128, 2) void attn_kernel(const u16* __restrict__ Qb,
                                                      const u16* __restrict__ Kb,
                                                      const u16* __restrict__ Vtb,
                                                      u16* __restrict__ Yb) {
  __shared__ u16 Ks[2][64 * 64];  // [t_local][d] seg-swizzled
  __shared__ u16 Vs[2][64 * 64];  // [d][t_local] seg-swizzled
  int bh = blockIdx.y;
  int b = bh >> 4, hh = bh & 15;
  int q0 = blockIdx.x * 64;
  const u16* Qh = Qb + (size_t)bh * 2048 * 64;
  const u16* Kh = Kb + (size_t)bh * 2048 * 64;
  const u16* Vh = Vtb + (size_t)bh * 64 * 2048;
  int tid = threadIdx.x, lane = tid & 63, wv = tid >> 6;
  int c5 = lane & 31, h = lane >> 5;

  // Q in registers: B-operand frags, qf[dc] = Q[q=c5][dc*16 + h*8 .. +7]
  const u16* Qrow = Qh + (size_t)(q0 + wv * 32 + c5) * 64;
  bf16x8 qf[4];
#pragma unroll
  for (int dc = 0; dc < 4; ++dc)
    qf[dc] = *(const bf16x8*)&Qrow[dc * 16 + h * 8];

  f32x16 acc0 = {}, acc1 = {};  // acc0[reg] = Y[q=(reg&3)+8*(reg>>2)+4h][d=c5], acc1: d=32+c5
  float mx = -1e30f, ls = 0.f;

  auto stage = [&](int buf, int t0) {
#pragma unroll
    for (int shot = 0; shot < 4; ++shot) {
      int ci = shot * 128 + tid;  // 512 slots of 16B each for K and V
      int row = ci >> 3, seg = ci & 7;
      int sseg = seg ^ (row & 7);
      gll16(Kh + (size_t)(t0 + row) * 64 + sseg * 8, &Ks[buf][ci * 8]);
      gll16(Vh + (size_t)row * 2048 + t0 + sseg * 8, &Vs[buf][ci * 8]);
    }
  };

  stage(0, 0);
  int cur = 0;
  for (int t0 = 0; t0 < 2048; t0 += 64) {
    __syncthreads();  // buf[cur] staged (barrier drains vmcnt)
    if (t0 + 64 < 2048) stage(cur ^ 1, t0 + 64);

    // ---- S^T = K x Q : two 32-k blocks ----
    f32x16 s0 = {}, s1 = {};
    __builtin_amdgcn_s_setprio(1);
#pragma unroll
    for (int dc = 0; dc < 4; ++dc) {
      int seg = dc * 2 + h;
      int ss = (seg ^ (c5 & 7)) * 8;
      bf16x8 kf0 = *(const bf16x8*)&Ks[cur][c5 * 64 + ss];
      bf16x8 kf1 = *(const bf16x8*)&Ks[cur][(32 + c5) * 64 + ss];
      s0 = mfma32(kf0, qf[dc], s0);
      s1 = mfma32(kf1, qf[dc], s1);
    }
    __builtin_amdgcn_s_setprio(0);

    // ---- softmax, fully in-register (log2 domain) ----
    float t8[8];
#pragma unroll
    for (int i = 0; i < 8; ++i)
      t8[i] = fmaxf(fmaxf(s0[i], s0[i + 8]), fmaxf(s1[i], s1[i + 8]));
#pragma unroll
    for (int st = 4; st >= 1; st >>= 1)
#pragma unroll
      for (int i = 0; i < 4; ++i)
        if (i < st) t8[i] = fmaxf(t8[i], t8[i + st]);
    // combine across h halves (lane ^ 32): both get fmax(lo, hi)
    float mtile = fmaxf(t8[0], __shfl_xor(t8[0], 32));
    if (!__all(mtile - mx <= 8.0f)) {  // defer-max rescale (rare)
      float mn = fmaxf(mx, mtile);
      float corr = exp2f(mx - mn);
      ls *= corr;
      mx = mn;
#pragma unroll
      for (int j = 0; j < 16; ++j) {
        float cb = __shfl(corr, (j & 3) + 8 * (j >> 2) + 4 * h, 64);
        acc0[j] *= cb;
        acc1[j] *= cb;
      }
    }
    // p = exp2(s - mx), in place; partial row-sum into ls
#pragma unroll
    for (int j = 0; j < 16; ++j) {
      s0[j] = exp2f(s0[j] - mx);
      s1[j] = exp2f(s1[j] - mx);
    }
#pragma unroll
    for (int i = 0; i < 8; ++i) t8[i] = (s0[i] + s0[i + 8]) + (s1[i] + s1[i + 8]);
#pragma unroll
    for (int st = 4; st >= 1; st >>= 1)
#pragma unroll
      for (int i = 0; i < 4; ++i)
        if (i < st) t8[i] += t8[i + st];
    ls += t8[0];

    // pack P to bf16 pairs: w[q2*2+pp] = (p[4q2+2pp], p[4q2+2pp+1])
    unsigned w0[8], w1[8];
#pragma unroll
    for (int q2 = 0; q2 < 4; ++q2)
#pragma unroll
      for (int pp = 0; pp < 2; ++pp) {
        w0[q2 * 2 + pp] = cvtpk(s0[q2 * 4 + 2 * pp], s0[q2 * 4 + 2 * pp + 1]);
        w1[q2 * 2 + pp] = cvtpk(s1[q2 * 4 + 2 * pp], s1[q2 * 4 + 2 * pp + 1]);
      }

    // ---- Y += P V ----
    __builtin_amdgcn_s_setprio(1);
#pragma unroll
    for (int kb = 0; kb < 2; ++kb) {
#pragma unroll
      for (int kk2 = 0; kk2 < 2; ++kk2) {
        // build A-frag via permlane32_swap: af = {A(pp0), A(pp1), B(pp0), B(pp1)}
        unsigned a0, b0, a1, b1;
        if (kb == 0) {
          a0 = w0[4 * kk2 + 0]; b0 = w0[4 * kk2 + 2];
          a1 = w0[4 * kk2 + 1]; b1 = w0[4 * kk2 + 3];
        } else {
          a0 = w1[4 * kk2 + 0]; b0 = w1[4 * kk2 + 2];
          a1 = w1[4 * kk2 + 1]; b1 = w1[4 * kk2 + 3];
        }
        plswap(a0, b0);
        plswap(a1, b1);
        u32x4 aw = {a0, a1, b0, b1};
        bf16x8 af = __builtin_bit_cast(bf16x8, aw);
        int seg = kb * 4 + kk2 * 2 + h;
        int ss = (seg ^ (c5 & 7)) * 8;
        bf16x8 vf0 = *(const bf16x8*)&Vs[cur][c5 * 64 + ss];
        bf16x8 vf1 = *(const bf16x8*)&Vs[cur][(32 + c5) * 64 + ss];
        acc0 = mfma32(af, vf0, acc0);
        acc1 = mfma32(af, vf1, acc1);
      }
    }
    __builtin_amdgcn_s_setprio(0);
    cur ^= 1;
  }

  // ---- epilogue: combine l across h halves (lane ^ 32), normalize, store ----
  ls += __shfl_xor(ls, 32);
  float inv = 1.0f / ls;
#pragma unroll
  for (int j = 0; j < 16; ++j) {
    int q = (j & 3) + 8 * (j >> 2) + 4 * h;
    float ib = __shfl(inv, q, 64);
    int trow = q0 + wv * 32 + q;
    size_t base = ((size_t)b * 2048 + trow) * 1024 + hh * 64;
    Yb[base + c5] = f2b(acc0[j] * ib);
    Yb[base + 32 + c5] = f2b(acc1[j] * ib);
  }
}

// ---------------- GEMM3: out = y @ w_proj^T + b_proj (fp32 out) ----------------
__global__ __launch_bounds__(256) void gemm_proj(const u16* __restrict__ A,
                                                 const u16* __restrict__ W,
                                                 const float* __restrict__ bias,
                                                 float* __restrict__ out) {
  __shared__ u16 As[128 * 64];
  __shared__ u16 Bs[128 * 64];
  const int K = 1024;
  int bn = blockIdx.x, bm = blockIdx.y;
  int tid = threadIdx.x, lane = tid & 63, w = tid >> 6;
  int wm = w >> 1, wn = w & 1, g = lane >> 4, c = lane & 15;
  f32x4 acc[4][4] = {};
  const u16* Arow = A + (size_t)(bm * 128) * K;
  const u16* Wrow = W + (size_t)(bn * 128) * K;
  for (int k0 = 0; k0 < K; k0 += 64) {
#pragma unroll
    for (int rr = 0; rr < 4; ++rr) {
      int ci = rr * 256 + tid;
      gll16(Arow + (ci >> 3) * K + k0 + (ci & 7) * 8, As + ci * 8);
    }
#pragma unroll
    for (int rr = 0; rr < 4; ++rr) {
      int ci = rr * 256 + tid;
      gll16(Wrow + (ci >> 3) * K + k0 + (ci & 7) * 8, Bs + ci * 8);
    }
    __syncthreads();
#pragma unroll
    for (int kk = 0; kk < 2; ++kk) {
      int koff = kk * 32 + g * 8;
      bf16x8 af[4], bfr[4];
#pragma unroll
      for (int mi = 0; mi < 4; ++mi)
        af[mi] = *(const bf16x8*)&As[(wm * 64 + mi * 16 + c) * 64 + koff];
#pragma unroll
      for (int ni = 0; ni < 4; ++ni)
        bfr[ni] = *(const bf16x8*)&Bs[(wn * 64 + ni * 16 + c) * 64 + koff];
#pragma unroll
      for (int mi = 0; mi < 4; ++mi)
#pragma unroll
        for (int ni = 0; ni < 4; ++ni)
          acc[mi][ni] = mfma16(af[mi], bfr[ni], acc[mi][ni]);
    }
    __syncthreads();
  }
#pragma unroll
  for (int mi = 0; mi < 4; ++mi)
#pragma unroll
    for (int ni = 0; ni < 4; ++ni)
#pragma unroll
      for (int r = 0; r < 4; ++r) {
        int row = bm * 128 + wm * 64 + mi * 16 + g * 4 + r;
        int col = bn * 128 + wn * 64 + ni * 16 + c;
        out[(size_t)row * 1024 + col] = acc[mi][ni][r] + bias[col];
      }
}

extern "C" void kernel_launch(void* const* d_in, const int* in_sizes, int n_in,
                              void* d_out, int out_size, void* d_ws, size_t ws_size,
                              hipStream_t stream) {
  const float* x      = (const float*)d_in[0];  // [2,2048,1024]
  const float* w_attn = (const float*)d_in[1];  // [3072,1024]
  const float* b_attn = (const float*)d_in[2];  // [3072]
  const float* w_proj = (const float*)d_in[3];  // [1024,1024]
  const float* b_proj = (const float*)d_in[4];  // [1024]
  float* out = (float*)d_out;

  u16* ws = (u16*)d_ws;
  const size_t XB  = 0;                 // 4096*1024
  const size_t WAB = XB + 4194304;      // 3072*1024
  const size_t WPB = WAB + 3145728;     // 1024*1024
  const size_t QB  = WPB + 1048576;     // 2*16*2048*64
  const size_t KB  = QB + 4194304;
  const size_t VTB = KB + 4194304;      // [bh][64][2048]
  const size_t YB  = VTB + 4194304;     // 4096*1024

  cvt3<<<8192, 256, 0, stream>>>(x, w_attn, w_proj, ws + XB, ws + WAB, ws + WPB);

  gemm_qkv<<<dim3(24, 32), 256, 0, stream>>>(ws + XB, ws + WAB, b_attn,
                                             ws + QB, ws + KB, ws + VTB);

  attn_kernel<<<dim3(32, 32), 128, 0, stream>>>(ws + QB, ws + KB, ws + VTB, ws + YB);

  gemm_proj<<<dim3(8, 32), 256, 0, stream>>>(ws + YB, ws + WPB, b_proj, out);
}

// Round 5
// 168.404 us; speedup vs baseline: 1.1356x; 1.1356x over previous
//
#include <hip/hip_runtime.h>
#include <hip/hip_bf16.h>

typedef unsigned short u16;
typedef __bf16 bf16x8 __attribute__((ext_vector_type(8)));
typedef float f32x4 __attribute__((ext_vector_type(4)));
typedef float f32x16 __attribute__((ext_vector_type(16)));
typedef unsigned u32x4 __attribute__((ext_vector_type(4)));

// B=2, T=2048, C=1024, H=16, hd=64. scale = 1/32; log2(e)/32 folded into Q.
#define QSCALE 0.045084220027780106f

__device__ __forceinline__ u16 f2b(float f) {
  unsigned x = __float_as_uint(f);
  unsigned r = (x + 0x7fffu + ((x >> 16) & 1u)) >> 16;  // RNE
  return (u16)r;
}

__device__ __forceinline__ void gll16(const void* g, void* l) {
  __builtin_amdgcn_global_load_lds((const __attribute__((address_space(1))) void*)g,
                                   (__attribute__((address_space(3))) void*)l, 16, 0, 0);
}

__device__ __forceinline__ f32x4 mfma16(bf16x8 a, bf16x8 b, f32x4 c) {
  return __builtin_amdgcn_mfma_f32_16x16x32_bf16(a, b, c, 0, 0, 0);
}
__device__ __forceinline__ f32x16 mfma32(bf16x8 a, bf16x8 b, f32x16 c) {
  return __builtin_amdgcn_mfma_f32_32x32x16_bf16(a, b, c, 0, 0, 0);
}

// v_permlane32_swap_b32 a,b : a' = {a_lo, b_lo}, b' = {a_hi, b_hi}
// ONLY safe with operands holding distinct values (identical values may be
// register-coalesced -> v_permlane32_swap_b32 v, v == half-swap, wrong).
__device__ __forceinline__ void plswap(unsigned& a, unsigned& b) {
  asm volatile("v_permlane32_swap_b32 %0, %1" : "+v"(a), "+v"(b));
}
__device__ __forceinline__ unsigned cvtpk(float lo, float hi) {
  unsigned r;
  asm("v_cvt_pk_bf16_f32 %0, %1, %2" : "=v"(r) : "v"(lo), "v"(hi));
  return r;
}

// ---------------- fp32 -> bf16 convert (all three tensors, one launch) ----------------
__global__ __launch_bounds__(256) void cvt3(const float* __restrict__ x,
                                            const float* __restrict__ wa,
                                            const float* __restrict__ wp,
                                            u16* __restrict__ dx,
                                            u16* __restrict__ dwa,
                                            u16* __restrict__ dwp) {
  const int N1 = 4194304, N2 = 3145728;
  int i = (blockIdx.x * 256 + threadIdx.x) * 4;
  const float* s;
  u16* d;
  int off;
  if (i < N1) { s = x; d = dx; off = i; }
  else if (i < N1 + N2) { s = wa; d = dwa; off = i - N1; }
  else { s = wp; d = dwp; off = i - N1 - N2; }
  float4 v = *(const float4*)(s + off);
  ushort4 o;
  o.x = f2b(v.x); o.y = f2b(v.y); o.z = f2b(v.z); o.w = f2b(v.w);
  *(ushort4*)(d + off) = o;
}

// ---------------- GEMM1: qkv = x @ w_attn^T + b_attn, scatter to Q/K/Vt ----------------
__global__ __launch_bounds__(256) void gemm_qkv(const u16* __restrict__ A,
                                                const u16* __restrict__ W,
                                                const float* __restrict__ bias,
                                                u16* __restrict__ Qb,
                                                u16* __restrict__ Kb,
                                                u16* __restrict__ Vtb) {
  __shared__ u16 As[128 * 64];
  __shared__ u16 Bs[128 * 64];
  const int K = 1024;
  int bn = blockIdx.x, bm = blockIdx.y;
  int tid = threadIdx.x, lane = tid & 63, w = tid >> 6;
  int wm = w >> 1, wn = w & 1, g = lane >> 4, c = lane & 15;
  f32x4 acc[4][4] = {};
  const u16* Arow = A + (size_t)(bm * 128) * K;
  const u16* Wrow = W + (size_t)(bn * 128) * K;
  for (int k0 = 0; k0 < K; k0 += 64) {
#pragma unroll
    for (int rr = 0; rr < 4; ++rr) {
      int ci = rr * 256 + tid;
      gll16(Arow + (ci >> 3) * K + k0 + (ci & 7) * 8, As + ci * 8);
    }
#pragma unroll
    for (int rr = 0; rr < 4; ++rr) {
      int ci = rr * 256 + tid;
      gll16(Wrow + (ci >> 3) * K + k0 + (ci & 7) * 8, Bs + ci * 8);
    }
    __syncthreads();
#pragma unroll
    for (int kk = 0; kk < 2; ++kk) {
      int koff = kk * 32 + g * 8;
      bf16x8 af[4], bfr[4];
#pragma unroll
      for (int mi = 0; mi < 4; ++mi)
        af[mi] = *(const bf16x8*)&As[(wm * 64 + mi * 16 + c) * 64 + koff];
#pragma unroll
      for (int ni = 0; ni < 4; ++ni)
        bfr[ni] = *(const bf16x8*)&Bs[(wn * 64 + ni * 16 + c) * 64 + koff];
#pragma unroll
      for (int mi = 0; mi < 4; ++mi)
#pragma unroll
        for (int ni = 0; ni < 4; ++ni)
          acc[mi][ni] = mfma16(af[mi], bfr[ni], acc[mi][ni]);
    }
    __syncthreads();
  }
#pragma unroll
  for (int mi = 0; mi < 4; ++mi)
#pragma unroll
    for (int ni = 0; ni < 4; ++ni)
#pragma unroll
      for (int r = 0; r < 4; ++r) {
        int row = bm * 128 + wm * 64 + mi * 16 + g * 4 + r;
        int col = bn * 128 + wn * 64 + ni * 16 + c;
        float v = acc[mi][ni][r] + bias[col];
        int b = row >> 11, t = row & 2047;
        int h = col / 192, j = col - h * 192;
        int bh = b * 16 + h;
        if (j < 64) {
          Qb[((size_t)bh * 2048 + t) * 64 + j] = f2b(v * QSCALE);
        } else if (j < 128) {
          Kb[((size_t)bh * 2048 + t) * 64 + (j - 64)] = f2b(v);
        } else {
          Vtb[((size_t)bh * 64 + (j - 128)) * 2048 + t] = f2b(v);
        }
      }
}

// ---------------- Flash attention, 32x32 swapped-QK^T + split-K ----------------
// grid: (T/64, B*H). 4 waves/block: wave = (wq, wk); wq picks q rows
// [wq*32,+32) of the block's 64; wk picks KV half [wk*1024, +1024).
// Each KV half iterates 32 tiles of KVB=32, staged in its own dbuf stream.
// Per lane: q = lane&31 (c5), h = lane>>5. S^T = mfma32(K, Q): lane holds
// S[t=(reg&3)+8*(reg>>2)+4h][q=c5]. V packed as [d&31][(d>>5)*32 + t] (128B rows).
// Halves merged at the end via LDS (flash rescale-combine).
__global__ __launch_bounds__(256, 4) void attn_kernel(const u16* __restrict__ Qb,
                                                      const u16* __restrict__ Kb,
                                                      const u16* __restrict__ Vtb,
                                                      u16* __restrict__ Yb) {
  // [stream][buf][K|V][32 rows * 64 u16], rows seg-swizzled (slot s holds seg s^(row&7))
  __shared__ u16 SMEM[2][2][2][2048];
  int bh = blockIdx.y;
  int b = bh >> 4, hh = bh & 15;
  int tid = threadIdx.x, lane = tid & 63, wv = tid >> 6;
  int wq = wv & 1, wk = wv >> 1;
  int c5 = lane & 31, h = lane >> 5;
  int q0 = blockIdx.x * 64 + wq * 32;
  const u16* Qh = Qb + (size_t)bh * 2048 * 64;
  const u16* Kh = Kb + (size_t)bh * 2048 * 64;
  const u16* Vh = Vtb + (size_t)bh * 64 * 2048;

  // Q in registers: B-operand frags, qf[dc] = Q[q=c5][dc*16 + h*8 .. +7]
  const u16* Qrow = Qh + (size_t)(q0 + c5) * 64;
  bf16x8 qf[4];
#pragma unroll
  for (int dc = 0; dc < 4; ++dc)
    qf[dc] = *(const bf16x8*)&Qrow[dc * 16 + h * 8];

  f32x16 acc0 = {}, acc1 = {};  // acc0[j]=Y[q=(j&3)+8*(j>>2)+4h][d=c5], acc1: d=32+c5
  float mx = -1e30f, ls = 0.f;

  // stage tile 'iter' of BOTH streams into buffer buf (16 KB, 4 gll16/thread)
  auto stagepair = [&](int buf, int iter) {
#pragma unroll
    for (int part = 0; part < 4; ++part) {
      int ci = part * 256 + tid;   // 0..1023 slots of 16B
      int st = ci >> 9;            // stream (kv half)
      int rem = ci & 511;
      int kv = rem >> 8;           // 0=K, 1=V
      int slot = rem & 255;
      int row = slot >> 3, seg = slot & 7;
      int sseg = seg ^ (row & 7);
      int t0 = st * 1024 + iter * 32;
      if (kv == 0) {
        gll16(Kh + (size_t)(t0 + row) * 64 + sseg * 8, &SMEM[st][buf][0][slot * 8]);
      } else {
        int dh = sseg >> 2, ksl = sseg & 3;
        gll16(Vh + (size_t)(dh * 32 + row) * 2048 + t0 + ksl * 8, &SMEM[st][buf][1][slot * 8]);
      }
    }
  };

  stagepair(0, 0);
  int cur = 0;
  for (int it = 0; it < 32; ++it) {
    __syncthreads();  // buf[cur] staged (barrier drains vmcnt); prior reads done
    if (it + 1 < 32) stagepair(cur ^ 1, it + 1);
    const u16* Kt = &SMEM[wk][cur][0][0];
    const u16* Vt = &SMEM[wk][cur][1][0];

    // ---- S^T = K x Q (one 32x32 tile, K-contraction d=64) ----
    f32x16 s0 = {};
    __builtin_amdgcn_s_setprio(1);
#pragma unroll
    for (int dc = 0; dc < 4; ++dc) {
      bf16x8 kf = *(const bf16x8*)&Kt[c5 * 64 + (((dc * 2 + h) ^ (c5 & 7)) * 8)];
      s0 = mfma32(kf, qf[dc], s0);
    }
    __builtin_amdgcn_s_setprio(0);

    // ---- softmax, in-register (log2 domain), defer-max THR=8 ----
    float t4[4];
#pragma unroll
    for (int i = 0; i < 4; ++i)
      t4[i] = fmaxf(fmaxf(s0[i], s0[i + 4]), fmaxf(s0[i + 8], s0[i + 12]));
    float mtile = fmaxf(fmaxf(t4[0], t4[1]), fmaxf(t4[2], t4[3]));
    mtile = fmaxf(mtile, __shfl_xor(mtile, 32));  // combine h halves
    if (!__all(mtile - mx <= 8.0f)) {
      float mn = fmaxf(mx, mtile);
      float corr = exp2f(mx - mn);
      ls *= corr;
      mx = mn;
#pragma unroll
      for (int j = 0; j < 16; ++j) {
        float cb = __shfl(corr, (j & 3) + 8 * (j >> 2) + 4 * h, 64);
        acc0[j] *= cb;
        acc1[j] *= cb;
      }
    }
#pragma unroll
    for (int j = 0; j < 16; ++j) s0[j] = exp2f(s0[j] - mx);
#pragma unroll
    for (int i = 0; i < 4; ++i)
      t4[i] = (s0[i] + s0[i + 4]) + (s0[i + 8] + s0[i + 12]);
    ls += (t4[0] + t4[1]) + (t4[2] + t4[3]);  // per-lane partial (h-split), merged later

    // pack P to bf16: w0[q2*2+pp] = (p[4q2+2pp], p[4q2+2pp+1])
    unsigned w0[8];
#pragma unroll
    for (int q2 = 0; q2 < 4; ++q2)
#pragma unroll
      for (int pp = 0; pp < 2; ++pp)
        w0[q2 * 2 + pp] = cvtpk(s0[q2 * 4 + 2 * pp], s0[q2 * 4 + 2 * pp + 1]);

    // ---- Y += P V ----
    __builtin_amdgcn_s_setprio(1);
#pragma unroll
    for (int ks2 = 0; ks2 < 2; ++ks2) {
      unsigned a0 = w0[4 * ks2 + 0], b0 = w0[4 * ks2 + 2];
      unsigned a1 = w0[4 * ks2 + 1], b1 = w0[4 * ks2 + 3];
      plswap(a0, b0);
      plswap(a1, b1);
      u32x4 aw = {a0, a1, b0, b1};
      bf16x8 af = __builtin_bit_cast(bf16x8, aw);
      bf16x8 vf0 = *(const bf16x8*)&Vt[c5 * 64 + (((ks2 * 2 + h) ^ (c5 & 7)) * 8)];
      bf16x8 vf1 = *(const bf16x8*)&Vt[c5 * 64 + (((4 + ks2 * 2 + h) ^ (c5 & 7)) * 8)];
      acc0 = mfma32(af, vf0, acc0);
      acc1 = mfma32(af, vf1, acc1);
    }
    __builtin_amdgcn_s_setprio(0);
    cur ^= 1;
  }

  // ---- merge the two KV halves (flash combine), then store ----
  float* MG = (float*)&SMEM[0][0][0][0];  // 32 KB free after last barrier
  int gi = wq * 64 + lane;
  __syncthreads();
  if (wk == 1) {
    MG[gi] = mx;
    MG[128 + gi] = ls;
#pragma unroll
    for (int j = 0; j < 16; ++j) {
      MG[256 + gi * 32 + j] = acc0[j];
      MG[256 + gi * 32 + 16 + j] = acc1[j];
    }
  }
  __syncthreads();
  if (wk == 0) {
    float mxB = MG[gi], lsB = MG[128 + gi];
    float m = fmaxf(mx, mxB);
    float cA = exp2f(mx - m), cB = exp2f(mxB - m);
    float l2 = ls * cA + lsB * cB;
    l2 += __shfl_xor(l2, 32);  // combine h halves
    float inv = 1.0f / l2;
#pragma unroll
    for (int j = 0; j < 16; ++j) {
      int q = (j & 3) + 8 * (j >> 2) + 4 * h;
      float cAq = __shfl(cA, q, 64);
      float cBq = __shfl(cB, q, 64);
      float ibq = __shfl(inv, q, 64);
      float y0 = (acc0[j] * cAq + MG[256 + gi * 32 + j] * cBq) * ibq;
      float y1 = (acc1[j] * cAq + MG[256 + gi * 32 + 16 + j] * cBq) * ibq;
      int trow = q0 + q;
      size_t base = ((size_t)b * 2048 + trow) * 1024 + hh * 64;
      Yb[base + c5] = f2b(y0);
      Yb[base + 32 + c5] = f2b(y1);
    }
  }
}

// ---------------- GEMM3: out = y @ w_proj^T + b_proj (fp32 out) ----------------
__global__ __launch_bounds__(256) void gemm_proj(const u16* __restrict__ A,
                                                 const u16* __restrict__ W,
                                                 const float* __restrict__ bias,
                                                 float* __restrict__ out) {
  __shared__ u16 As[128 * 64];
  __shared__ u16 Bs[128 * 64];
  const int K = 1024;
  int bn = blockIdx.x, bm = blockIdx.y;
  int tid = threadIdx.x, lane = tid & 63, w = tid >> 6;
  int wm = w >> 1, wn = w & 1, g = lane >> 4, c = lane & 15;
  f32x4 acc[4][4] = {};
  const u16* Arow = A + (size_t)(bm * 128) * K;
  const u16* Wrow = W + (size_t)(bn * 128) * K;
  for (int k0 = 0; k0 < K; k0 += 64) {
#pragma unroll
    for (int rr = 0; rr < 4; ++rr) {
      int ci = rr * 256 + tid;
      gll16(Arow + (ci >> 3) * K + k0 + (ci & 7) * 8, As + ci * 8);
    }
#pragma unroll
    for (int rr = 0; rr < 4; ++rr) {
      int ci = rr * 256 + tid;
      gll16(Wrow + (ci >> 3) * K + k0 + (ci & 7) * 8, Bs + ci * 8);
    }
    __syncthreads();
#pragma unroll
    for (int kk = 0; kk < 2; ++kk) {
      int koff = kk * 32 + g * 8;
      bf16x8 af[4], bfr[4];
#pragma unroll
      for (int mi = 0; mi < 4; ++mi)
        af[mi] = *(const bf16x8*)&As[(wm * 64 + mi * 16 + c) * 64 + koff];
#pragma unroll
      for (int ni = 0; ni < 4; ++ni)
        bfr[ni] = *(const bf16x8*)&Bs[(wn * 64 + ni * 16 + c) * 64 + koff];
#pragma unroll
      for (int mi = 0; mi < 4; ++mi)
#pragma unroll
        for (int ni = 0; ni < 4; ++ni)
          acc[mi][ni] = mfma16(af[mi], bfr[ni], acc[mi][ni]);
    }
    __syncthreads();
  }
#pragma unroll
  for (int mi = 0; mi < 4; ++mi)
#pragma unroll
    for (int ni = 0; ni < 4; ++ni)
#pragma unroll
      for (int r = 0; r < 4; ++r) {
        int row = bm * 128 + wm * 64 + mi * 16 + g * 4 + r;
        int col = bn * 128 + wn * 64 + ni * 16 + c;
        out[(size_t)row * 1024 + col] = acc[mi][ni][r] + bias[col];
      }
}

extern "C" void kernel_launch(void* const* d_in, const int* in_sizes, int n_in,
                              void* d_out, int out_size, void* d_ws, size_t ws_size,
                              hipStream_t stream) {
  const float* x      = (const float*)d_in[0];  // [2,2048,1024]
  const float* w_attn = (const float*)d_in[1];  // [3072,1024]
  const float* b_attn = (const float*)d_in[2];  // [3072]
  const float* w_proj = (const float*)d_in[3];  // [1024,1024]
  const float* b_proj = (const float*)d_in[4];  // [1024]
  float* out = (float*)d_out;

  u16* ws = (u16*)d_ws;
  const size_t XB  = 0;                 // 4096*1024
  const size_t WAB = XB + 4194304;      // 3072*1024
  const size_t WPB = WAB + 3145728;     // 1024*1024
  const size_t QB  = WPB + 1048576;     // 2*16*2048*64
  const size_t KB  = QB + 4194304;
  const size_t VTB = KB + 4194304;      // [bh][64][2048]
  const size_t YB  = VTB + 4194304;     // 4096*1024

  cvt3<<<8192, 256, 0, stream>>>(x, w_attn, w_proj, ws + XB, ws + WAB, ws + WPB);

  gemm_qkv<<<dim3(24, 32), 256, 0, stream>>>(ws + XB, ws + WAB, b_attn,
                                             ws + QB, ws + KB, ws + VTB);

  attn_kernel<<<dim3(32, 32), 256, 0, stream>>>(ws + QB, ws + KB, ws + VTB, ws + YB);

  gemm_proj<<<dim3(8, 32), 256, 0, stream>>>(ws + YB, ws + WPB, b_proj, out);
}

// Round 6
// 150.375 us; speedup vs baseline: 1.2718x; 1.1199x over previous
//
#include <hip/hip_runtime.h>
#include <hip/hip_bf16.h>

typedef unsigned short u16;
typedef __bf16 bf16x8 __attribute__((ext_vector_type(8)));
typedef float f32x4 __attribute__((ext_vector_type(4)));
typedef float f32x16 __attribute__((ext_vector_type(16)));
typedef unsigned u32x4 __attribute__((ext_vector_type(4)));

// B=2, T=2048, C=1024, H=16, hd=64. scale = 1/32; log2(e)/32 folded into Q.
#define QSCALE 0.045084220027780106f

__device__ __forceinline__ u16 f2b(float f) {
  unsigned x = __float_as_uint(f);
  unsigned r = (x + 0x7fffu + ((x >> 16) & 1u)) >> 16;  // RNE
  return (u16)r;
}

__device__ __forceinline__ void gll16(const void* g, void* l) {
  __builtin_amdgcn_global_load_lds((const __attribute__((address_space(1))) void*)g,
                                   (__attribute__((address_space(3))) void*)l, 16, 0, 0);
}

__device__ __forceinline__ f32x4 mfma16(bf16x8 a, bf16x8 b, f32x4 c) {
  return __builtin_amdgcn_mfma_f32_16x16x32_bf16(a, b, c, 0, 0, 0);
}
__device__ __forceinline__ f32x16 mfma32(bf16x8 a, bf16x8 b, f32x16 c) {
  return __builtin_amdgcn_mfma_f32_32x32x16_bf16(a, b, c, 0, 0, 0);
}

// v_permlane32_swap_b32 a,b : a' = {a_lo, b_lo}, b' = {a_hi, b_hi}
// ONLY safe with operands holding distinct values (identical values may be
// register-coalesced -> v_permlane32_swap_b32 v, v == half-swap, wrong).
__device__ __forceinline__ void plswap(unsigned& a, unsigned& b) {
  asm volatile("v_permlane32_swap_b32 %0, %1" : "+v"(a), "+v"(b));
}
__device__ __forceinline__ unsigned cvtpk(float lo, float hi) {
  unsigned r;
  asm("v_cvt_pk_bf16_f32 %0, %1, %2" : "=v"(r) : "v"(lo), "v"(hi));
  return r;
}

// ---------------- fp32 -> bf16 convert (all three tensors, one launch) ----------------
__global__ __launch_bounds__(256) void cvt3(const float* __restrict__ x,
                                            const float* __restrict__ wa,
                                            const float* __restrict__ wp,
                                            u16* __restrict__ dx,
                                            u16* __restrict__ dwa,
                                            u16* __restrict__ dwp) {
  const int N1 = 4194304, N2 = 3145728;
  int i = (blockIdx.x * 256 + threadIdx.x) * 4;
  const float* s;
  u16* d;
  int off;
  if (i < N1) { s = x; d = dx; off = i; }
  else if (i < N1 + N2) { s = wa; d = dwa; off = i - N1; }
  else { s = wp; d = dwp; off = i - N1 - N2; }
  float4 v = *(const float4*)(s + off);
  ushort4 o;
  o.x = f2b(v.x); o.y = f2b(v.y); o.z = f2b(v.z); o.w = f2b(v.w);
  *(ushort4*)(d + off) = o;
}

// ---------------- GEMM1: qkv = x @ w_attn^T + b_attn, scatter to Q/K/Vt ----------------
// Double-buffered single-barrier K-loop; LDS rows seg-XOR-swizzled
// (slot s of row r holds global 16B-seg s^(r&7); read seg q at slot q^(r&7)).
__global__ __launch_bounds__(256) void gemm_qkv(const u16* __restrict__ A,
                                                const u16* __restrict__ W,
                                                const float* __restrict__ bias,
                                                u16* __restrict__ Qb,
                                                u16* __restrict__ Kb,
                                                u16* __restrict__ Vtb) {
  __shared__ u16 As[2][128 * 64];
  __shared__ u16 Bs[2][128 * 64];
  const int K = 1024;
  int bn = blockIdx.x, bm = blockIdx.y;
  int tid = threadIdx.x, lane = tid & 63, w = tid >> 6;
  int wm = w >> 1, wn = w & 1, g = lane >> 4, c = lane & 15;
  f32x4 acc[4][4] = {};
  const u16* Arow = A + (size_t)(bm * 128) * K;
  const u16* Wrow = W + (size_t)(bn * 128) * K;

  auto stage = [&](int buf, int k0) {
#pragma unroll
    for (int rr = 0; rr < 4; ++rr) {
      int ci = rr * 256 + tid;
      int row = ci >> 3, sseg = (ci & 7) ^ (row & 7);
      gll16(Arow + (size_t)row * K + k0 + sseg * 8, &As[buf][ci * 8]);
    }
#pragma unroll
    for (int rr = 0; rr < 4; ++rr) {
      int ci = rr * 256 + tid;
      int row = ci >> 3, sseg = (ci & 7) ^ (row & 7);
      gll16(Wrow + (size_t)row * K + k0 + sseg * 8, &Bs[buf][ci * 8]);
    }
  };

  stage(0, 0);
  int cur = 0;
  for (int k0 = 0; k0 < K; k0 += 64) {
    __syncthreads();  // drains vmcnt: buf[cur] staged; prior LDS reads done
    if (k0 + 64 < K) stage(cur ^ 1, k0 + 64);
#pragma unroll
    for (int kk = 0; kk < 2; ++kk) {
      int q = kk * 4 + g;
      bf16x8 af[4], bfr[4];
#pragma unroll
      for (int mi = 0; mi < 4; ++mi) {
        int row = wm * 64 + mi * 16 + c;
        af[mi] = *(const bf16x8*)&As[cur][row * 64 + ((q ^ (c & 7)) * 8)];
      }
#pragma unroll
      for (int ni = 0; ni < 4; ++ni) {
        int row = wn * 64 + ni * 16 + c;
        bfr[ni] = *(const bf16x8*)&Bs[cur][row * 64 + ((q ^ (c & 7)) * 8)];
      }
#pragma unroll
      for (int mi = 0; mi < 4; ++mi)
#pragma unroll
        for (int ni = 0; ni < 4; ++ni)
          acc[mi][ni] = mfma16(af[mi], bfr[ni], acc[mi][ni]);
    }
    cur ^= 1;
  }
#pragma unroll
  for (int mi = 0; mi < 4; ++mi)
#pragma unroll
    for (int ni = 0; ni < 4; ++ni)
#pragma unroll
      for (int r = 0; r < 4; ++r) {
        int row = bm * 128 + wm * 64 + mi * 16 + g * 4 + r;
        int col = bn * 128 + wn * 64 + ni * 16 + c;
        float v = acc[mi][ni][r] + bias[col];
        int b = row >> 11, t = row & 2047;
        int h = col / 192, j = col - h * 192;
        int bh = b * 16 + h;
        if (j < 64) {
          Qb[((size_t)bh * 2048 + t) * 64 + j] = f2b(v * QSCALE);
        } else if (j < 128) {
          Kb[((size_t)bh * 2048 + t) * 64 + (j - 64)] = f2b(v);
        } else {
          Vtb[((size_t)bh * 64 + (j - 128)) * 2048 + t] = f2b(v);
        }
      }
}

// ---------------- Flash attention, 32x32 swapped-QK^T + split-K ----------------
// grid: (T/64, B*H). 4 waves/block: wave = (wq, wk); wq picks q rows
// [wq*32,+32) of the block's 64; wk picks KV half [wk*1024, +1024).
// Each KV half iterates 32 tiles of KVB=32, staged in its own dbuf stream.
// Per lane: q = lane&31 (c5), h = lane>>5. S^T = mfma32(K, Q): lane holds
// S[t=(reg&3)+8*(reg>>2)+4h][q=c5]. V packed as [d&31][(d>>5)*32 + t] (128B rows).
// Halves merged at the end via LDS (flash rescale-combine).
__global__ __launch_bounds__(256, 4) void attn_kernel(const u16* __restrict__ Qb,
                                                      const u16* __restrict__ Kb,
                                                      const u16* __restrict__ Vtb,
                                                      u16* __restrict__ Yb) {
  // [stream][buf][K|V][32 rows * 64 u16], rows seg-swizzled (slot s holds seg s^(row&7))
  __shared__ u16 SMEM[2][2][2][2048];
  int bh = blockIdx.y;
  int b = bh >> 4, hh = bh & 15;
  int tid = threadIdx.x, lane = tid & 63, wv = tid >> 6;
  int wq = wv & 1, wk = wv >> 1;
  int c5 = lane & 31, h = lane >> 5;
  int q0 = blockIdx.x * 64 + wq * 32;
  const u16* Qh = Qb + (size_t)bh * 2048 * 64;
  const u16* Kh = Kb + (size_t)bh * 2048 * 64;
  const u16* Vh = Vtb + (size_t)bh * 64 * 2048;

  // Q in registers: B-operand frags, qf[dc] = Q[q=c5][dc*16 + h*8 .. +7]
  const u16* Qrow = Qh + (size_t)(q0 + c5) * 64;
  bf16x8 qf[4];
#pragma unroll
  for (int dc = 0; dc < 4; ++dc)
    qf[dc] = *(const bf16x8*)&Qrow[dc * 16 + h * 8];

  f32x16 acc0 = {}, acc1 = {};  // acc0[j]=Y[q=(j&3)+8*(j>>2)+4h][d=c5], acc1: d=32+c5
  float mx = -1e30f, ls = 0.f;

  // stage tile 'iter' of BOTH streams into buffer buf (16 KB, 4 gll16/thread)
  auto stagepair = [&](int buf, int iter) {
#pragma unroll
    for (int part = 0; part < 4; ++part) {
      int ci = part * 256 + tid;   // 0..1023 slots of 16B
      int st = ci >> 9;            // stream (kv half)
      int rem = ci & 511;
      int kv = rem >> 8;           // 0=K, 1=V
      int slot = rem & 255;
      int row = slot >> 3, seg = slot & 7;
      int sseg = seg ^ (row & 7);
      int t0 = st * 1024 + iter * 32;
      if (kv == 0) {
        gll16(Kh + (size_t)(t0 + row) * 64 + sseg * 8, &SMEM[st][buf][0][slot * 8]);
      } else {
        int dh = sseg >> 2, ksl = sseg & 3;
        gll16(Vh + (size_t)(dh * 32 + row) * 2048 + t0 + ksl * 8, &SMEM[st][buf][1][slot * 8]);
      }
    }
  };

  stagepair(0, 0);
  int cur = 0;
  for (int it = 0; it < 32; ++it) {
    __syncthreads();  // buf[cur] staged (barrier drains vmcnt); prior reads done
    if (it + 1 < 32) stagepair(cur ^ 1, it + 1);
    const u16* Kt = &SMEM[wk][cur][0][0];
    const u16* Vt = &SMEM[wk][cur][1][0];

    // ---- S^T = K x Q (one 32x32 tile, K-contraction d=64) ----
    f32x16 s0 = {};
    __builtin_amdgcn_s_setprio(1);
#pragma unroll
    for (int dc = 0; dc < 4; ++dc) {
      bf16x8 kf = *(const bf16x8*)&Kt[c5 * 64 + (((dc * 2 + h) ^ (c5 & 7)) * 8)];
      s0 = mfma32(kf, qf[dc], s0);
    }
    __builtin_amdgcn_s_setprio(0);

    // ---- softmax, in-register (log2 domain), defer-max THR=8 ----
    float t4[4];
#pragma unroll
    for (int i = 0; i < 4; ++i)
      t4[i] = fmaxf(fmaxf(s0[i], s0[i + 4]), fmaxf(s0[i + 8], s0[i + 12]));
    float mtile = fmaxf(fmaxf(t4[0], t4[1]), fmaxf(t4[2], t4[3]));
    mtile = fmaxf(mtile, __shfl_xor(mtile, 32));  // combine h halves
    if (!__all(mtile - mx <= 8.0f)) {
      float mn = fmaxf(mx, mtile);
      float corr = exp2f(mx - mn);
      ls *= corr;
      mx = mn;
#pragma unroll
      for (int j = 0; j < 16; ++j) {
        float cb = __shfl(corr, (j & 3) + 8 * (j >> 2) + 4 * h, 64);
        acc0[j] *= cb;
        acc1[j] *= cb;
      }
    }
#pragma unroll
    for (int j = 0; j < 16; ++j) s0[j] = exp2f(s0[j] - mx);
#pragma unroll
    for (int i = 0; i < 4; ++i)
      t4[i] = (s0[i] + s0[i + 4]) + (s0[i + 8] + s0[i + 12]);
    ls += (t4[0] + t4[1]) + (t4[2] + t4[3]);  // per-lane partial (h-split), merged later

    // pack P to bf16: w0[q2*2+pp] = (p[4q2+2pp], p[4q2+2pp+1])
    unsigned w0[8];
#pragma unroll
    for (int q2 = 0; q2 < 4; ++q2)
#pragma unroll
      for (int pp = 0; pp < 2; ++pp)
        w0[q2 * 2 + pp] = cvtpk(s0[q2 * 4 + 2 * pp], s0[q2 * 4 + 2 * pp + 1]);

    // ---- Y += P V ----
    __builtin_amdgcn_s_setprio(1);
#pragma unroll
    for (int ks2 = 0; ks2 < 2; ++ks2) {
      unsigned a0 = w0[4 * ks2 + 0], b0 = w0[4 * ks2 + 2];
      unsigned a1 = w0[4 * ks2 + 1], b1 = w0[4 * ks2 + 3];
      plswap(a0, b0);
      plswap(a1, b1);
      u32x4 aw = {a0, a1, b0, b1};
      bf16x8 af = __builtin_bit_cast(bf16x8, aw);
      bf16x8 vf0 = *(const bf16x8*)&Vt[c5 * 64 + (((ks2 * 2 + h) ^ (c5 & 7)) * 8)];
      bf16x8 vf1 = *(const bf16x8*)&Vt[c5 * 64 + (((4 + ks2 * 2 + h) ^ (c5 & 7)) * 8)];
      acc0 = mfma32(af, vf0, acc0);
      acc1 = mfma32(af, vf1, acc1);
    }
    __builtin_amdgcn_s_setprio(0);
    cur ^= 1;
  }

  // ---- merge the two KV halves (flash combine), then store ----
  float* MG = (float*)&SMEM[0][0][0][0];  // 32 KB free after last barrier
  int gi = wq * 64 + lane;
  __syncthreads();
  if (wk == 1) {
    MG[gi] = mx;
    MG[128 + gi] = ls;
#pragma unroll
    for (int j = 0; j < 16; ++j) {
      MG[256 + gi * 32 + j] = acc0[j];
      MG[256 + gi * 32 + 16 + j] = acc1[j];
    }
  }
  __syncthreads();
  if (wk == 0) {
    float mxB = MG[gi], lsB = MG[128 + gi];
    float m = fmaxf(mx, mxB);
    float cA = exp2f(mx - m), cB = exp2f(mxB - m);
    float l2 = ls * cA + lsB * cB;
    l2 += __shfl_xor(l2, 32);  // combine h halves
    float inv = 1.0f / l2;
#pragma unroll
    for (int j = 0; j < 16; ++j) {
      int q = (j & 3) + 8 * (j >> 2) + 4 * h;
      float cAq = __shfl(cA, q, 64);
      float cBq = __shfl(cB, q, 64);
      float ibq = __shfl(inv, q, 64);
      float y0 = (acc0[j] * cAq + MG[256 + gi * 32 + j] * cBq) * ibq;
      float y1 = (acc1[j] * cAq + MG[256 + gi * 32 + 16 + j] * cBq) * ibq;
      int trow = q0 + q;
      size_t base = ((size_t)b * 2048 + trow) * 1024 + hh * 64;
      Yb[base + c5] = f2b(y0);
      Yb[base + 32 + c5] = f2b(y1);
    }
  }
}

// ---------------- GEMM3: out = y @ w_proj^T + b_proj (fp32 out) ----------------
__global__ __launch_bounds__(256) void gemm_proj(const u16* __restrict__ A,
                                                 const u16* __restrict__ W,
                                                 const float* __restrict__ bias,
                                                 float* __restrict__ out) {
  __shared__ u16 As[2][128 * 64];
  __shared__ u16 Bs[2][128 * 64];
  const int K = 1024;
  int bn = blockIdx.x, bm = blockIdx.y;
  int tid = threadIdx.x, lane = tid & 63, w = tid >> 6;
  int wm = w >> 1, wn = w & 1, g = lane >> 4, c = lane & 15;
  f32x4 acc[4][4] = {};
  const u16* Arow = A + (size_t)(bm * 128) * K;
  const u16* Wrow = W + (size_t)(bn * 128) * K;

  auto stage = [&](int buf, int k0) {
#pragma unroll
    for (int rr = 0; rr < 4; ++rr) {
      int ci = rr * 256 + tid;
      int row = ci >> 3, sseg = (ci & 7) ^ (row & 7);
      gll16(Arow + (size_t)row * K + k0 + sseg * 8, &As[buf][ci * 8]);
    }
#pragma unroll
    for (int rr = 0; rr < 4; ++rr) {
      int ci = rr * 256 + tid;
      int row = ci >> 3, sseg = (ci & 7) ^ (row & 7);
      gll16(Wrow + (size_t)row * K + k0 + sseg * 8, &Bs[buf][ci * 8]);
    }
  };

  stage(0, 0);
  int cur = 0;
  for (int k0 = 0; k0 < K; k0 += 64) {
    __syncthreads();
    if (k0 + 64 < K) stage(cur ^ 1, k0 + 64);
#pragma unroll
    for (int kk = 0; kk < 2; ++kk) {
      int q = kk * 4 + g;
      bf16x8 af[4], bfr[4];
#pragma unroll
      for (int mi = 0; mi < 4; ++mi) {
        int row = wm * 64 + mi * 16 + c;
        af[mi] = *(const bf16x8*)&As[cur][row * 64 + ((q ^ (c & 7)) * 8)];
      }
#pragma unroll
      for (int ni = 0; ni < 4; ++ni) {
        int row = wn * 64 + ni * 16 + c;
        bfr[ni] = *(const bf16x8*)&Bs[cur][row * 64 + ((q ^ (c & 7)) * 8)];
      }
#pragma unroll
      for (int mi = 0; mi < 4; ++mi)
#pragma unroll
        for (int ni = 0; ni < 4; ++ni)
          acc[mi][ni] = mfma16(af[mi], bfr[ni], acc[mi][ni]);
    }
    cur ^= 1;
  }
#pragma unroll
  for (int mi = 0; mi < 4; ++mi)
#pragma unroll
    for (int ni = 0; ni < 4; ++ni)
#pragma unroll
      for (int r = 0; r < 4; ++r) {
        int row = bm * 128 + wm * 64 + mi * 16 + g * 4 + r;
        int col = bn * 128 + wn * 64 + ni * 16 + c;
        out[(size_t)row * 1024 + col] = acc[mi][ni][r] + bias[col];
      }
}

extern "C" void kernel_launch(void* const* d_in, const int* in_sizes, int n_in,
                              void* d_out, int out_size, void* d_ws, size_t ws_size,
                              hipStream_t stream) {
  const float* x      = (const float*)d_in[0];  // [2,2048,1024]
  const float* w_attn = (const float*)d_in[1];  // [3072,1024]
  const float* b_attn = (const float*)d_in[2];  // [3072]
  const float* w_proj = (const float*)d_in[3];  // [1024,1024]
  const float* b_proj = (const float*)d_in[4];  // [1024]
  float* out = (float*)d_out;

  u16* ws = (u16*)d_ws;
  const size_t XB  = 0;                 // 4096*1024
  const size_t WAB = XB + 4194304;      // 3072*1024
  const size_t WPB = WAB + 3145728;     // 1024*1024
  const size_t QB  = WPB + 1048576;     // 2*16*2048*64
  const size_t KB  = QB + 4194304;
  const size_t VTB = KB + 4194304;      // [bh][64][2048]
  const size_t YB  = VTB + 4194304;     // 4096*1024

  cvt3<<<8192, 256, 0, stream>>>(x, w_attn, w_proj, ws + XB, ws + WAB, ws + WPB);

  gemm_qkv<<<dim3(24, 32), 256, 0, stream>>>(ws + XB, ws + WAB, b_attn,
                                             ws + QB, ws + KB, ws + VTB);

  attn_kernel<<<dim3(32, 32), 256, 0, stream>>>(ws + QB, ws + KB, ws + VTB, ws + YB);

  gemm_proj<<<dim3(8, 32), 256, 0, stream>>>(ws + YB, ws + WPB, b_proj, out);
}

// Round 7
// 145.712 us; speedup vs baseline: 1.3124x; 1.0320x over previous
//
#include <hip/hip_runtime.h>
#include <hip/hip_bf16.h>

typedef unsigned short u16;
typedef __bf16 bf16x8 __attribute__((ext_vector_type(8)));
typedef float f32x4 __attribute__((ext_vector_type(4)));
typedef float f32x16 __attribute__((ext_vector_type(16)));
typedef unsigned u32x4 __attribute__((ext_vector_type(4)));

// B=2, T=2048, C=1024, H=16, hd=64. scale = 1/32; log2(e)/32 folded into Q.
#define QSCALE 0.045084220027780106f

__device__ __forceinline__ u16 f2b(float f) {
  unsigned x = __float_as_uint(f);
  unsigned r = (x + 0x7fffu + ((x >> 16) & 1u)) >> 16;  // RNE
  return (u16)r;
}

__device__ __forceinline__ void gll16(const void* g, void* l) {
  __builtin_amdgcn_global_load_lds((const __attribute__((address_space(1))) void*)g,
                                   (__attribute__((address_space(3))) void*)l, 16, 0, 0);
}

__device__ __forceinline__ f32x4 mfma16(bf16x8 a, bf16x8 b, f32x4 c) {
  return __builtin_amdgcn_mfma_f32_16x16x32_bf16(a, b, c, 0, 0, 0);
}
__device__ __forceinline__ f32x16 mfma32(bf16x8 a, bf16x8 b, f32x16 c) {
  return __builtin_amdgcn_mfma_f32_32x32x16_bf16(a, b, c, 0, 0, 0);
}

// v_permlane32_swap_b32 a,b : a' = {a_lo, b_lo}, b' = {a_hi, b_hi}
// ONLY safe with operands holding distinct values (identical values may be
// register-coalesced -> v_permlane32_swap_b32 v, v == half-swap, wrong).
__device__ __forceinline__ void plswap(unsigned& a, unsigned& b) {
  asm volatile("v_permlane32_swap_b32 %0, %1" : "+v"(a), "+v"(b));
}
__device__ __forceinline__ unsigned cvtpk(float lo, float hi) {
  unsigned r;
  asm("v_cvt_pk_bf16_f32 %0, %1, %2" : "=v"(r) : "v"(lo), "v"(hi));
  return r;
}

// ---------------- fp32 -> bf16 convert (all three tensors, one launch) ----------------
__global__ __launch_bounds__(256) void cvt3(const float* __restrict__ x,
                                            const float* __restrict__ wa,
                                            const float* __restrict__ wp,
                                            u16* __restrict__ dx,
                                            u16* __restrict__ dwa,
                                            u16* __restrict__ dwp) {
  const int N1 = 4194304, N2 = 3145728;
  int i = (blockIdx.x * 256 + threadIdx.x) * 4;
  const float* s;
  u16* d;
  int off;
  if (i < N1) { s = x; d = dx; off = i; }
  else if (i < N1 + N2) { s = wa; d = dwa; off = i - N1; }
  else { s = wp; d = dwp; off = i - N1 - N2; }
  float4 v = *(const float4*)(s + off);
  ushort4 o;
  o.x = f2b(v.x); o.y = f2b(v.y); o.z = f2b(v.z); o.w = f2b(v.w);
  *(ushort4*)(d + off) = o;
}

// ---------------- GEMM1: qkv = x @ w_attn^T + b_attn, scatter to Q/K/Vt ----------------
// 256x256 tile, 8 waves (2M x 4N), BK=64, double-buffered single-barrier loop.
// LDS rows seg-XOR-swizzled (slot s of row r holds 16B-seg s^(r&7)).
// Grid 192 blocks = one residency round; XCD patch swizzle: each XCD gets a
// 4bm x 6bn patch (A 2MB + W 3MB ~ fits its private 4MB L2).
__global__ __launch_bounds__(512) void gemm_qkv(const u16* __restrict__ A,
                                                const u16* __restrict__ W,
                                                const float* __restrict__ bias,
                                                u16* __restrict__ Qb,
                                                u16* __restrict__ Kb,
                                                u16* __restrict__ Vtb) {
  __shared__ u16 As[2][256 * 64];
  __shared__ u16 Bs[2][256 * 64];
  const int K = 1024;
  int o = blockIdx.x;             // 0..191
  int xcd = o & 7, li = o >> 3;   // li 0..23
  int bm = (xcd >> 1) * 4 + li / 6;   // 0..15
  int bn = (xcd & 1) * 6 + li % 6;    // 0..11
  int tid = threadIdx.x, lane = tid & 63, w = tid >> 6;
  int wm = w >> 2, wn = w & 3, g = lane >> 4, c = lane & 15;
  f32x4 acc[8][4] = {};
  const u16* Arow = A + (size_t)(bm * 256) * K;
  const u16* Wrow = W + (size_t)(bn * 256) * K;

  // hoisted staging addresses: 4 slots each for A and B per thread
  const u16* asrc[4];
  const u16* bsrc[4];
  int sdst[4];
#pragma unroll
  for (int rr = 0; rr < 4; ++rr) {
    int ci = rr * 512 + tid;  // 0..2047 16B-slots
    int row = ci >> 3, sseg = (ci & 7) ^ (row & 7);
    asrc[rr] = Arow + (size_t)row * K + sseg * 8;
    bsrc[rr] = Wrow + (size_t)row * K + sseg * 8;
    sdst[rr] = ci * 8;
  }
  auto stage = [&](int buf) {
#pragma unroll
    for (int rr = 0; rr < 4; ++rr) gll16(asrc[rr], &As[buf][sdst[rr]]);
#pragma unroll
    for (int rr = 0; rr < 4; ++rr) gll16(bsrc[rr], &Bs[buf][sdst[rr]]);
#pragma unroll
    for (int rr = 0; rr < 4; ++rr) { asrc[rr] += 64; bsrc[rr] += 64; }
  };

  stage(0);
  int cur = 0;
  for (int k0 = 0; k0 < K; k0 += 64) {
    __syncthreads();  // drains vmcnt: buf[cur] staged; prior LDS reads done
    if (k0 + 64 < K) stage(cur ^ 1);
#pragma unroll
    for (int kk = 0; kk < 2; ++kk) {
      bf16x8 af[8], bfr[4];
#pragma unroll
      for (int mi = 0; mi < 8; ++mi) {
        int row = wm * 128 + mi * 16 + c;
        af[mi] = *(const bf16x8*)&As[cur][row * 64 + (((kk * 4 + g) ^ (row & 7)) * 8)];
      }
#pragma unroll
      for (int ni = 0; ni < 4; ++ni) {
        int row = wn * 64 + ni * 16 + c;
        bfr[ni] = *(const bf16x8*)&Bs[cur][row * 64 + (((kk * 4 + g) ^ (row & 7)) * 8)];
      }
      __builtin_amdgcn_s_setprio(1);
#pragma unroll
      for (int mi = 0; mi < 8; ++mi)
#pragma unroll
        for (int ni = 0; ni < 4; ++ni)
          acc[mi][ni] = mfma16(af[mi], bfr[ni], acc[mi][ni]);
      __builtin_amdgcn_s_setprio(0);
    }
    cur ^= 1;
  }
#pragma unroll
  for (int mi = 0; mi < 8; ++mi)
#pragma unroll
    for (int ni = 0; ni < 4; ++ni)
#pragma unroll
      for (int r = 0; r < 4; ++r) {
        int row = bm * 256 + wm * 128 + mi * 16 + g * 4 + r;
        int col = bn * 256 + wn * 64 + ni * 16 + c;
        float v = acc[mi][ni][r] + bias[col];
        int b = row >> 11, t = row & 2047;
        int h = col / 192, j = col - h * 192;
        int bh = b * 16 + h;
        if (j < 64) {
          Qb[((size_t)bh * 2048 + t) * 64 + j] = f2b(v * QSCALE);
        } else if (j < 128) {
          Kb[((size_t)bh * 2048 + t) * 64 + (j - 64)] = f2b(v);
        } else {
          Vtb[((size_t)bh * 64 + (j - 128)) * 2048 + t] = f2b(v);
        }
      }
}

// ---------------- Flash attention, 32x32 swapped-QK^T + split-K ----------------
// grid: (T/64, B*H). 4 waves/block: wave = (wq, wk); wq picks q rows
// [wq*32,+32); wk picks KV half. Staging addresses hoisted (fixed per-thread
// src pointer + constant stride). Merge accumulator stride padded to 33 f32.
__global__ __launch_bounds__(256, 4) void attn_kernel(const u16* __restrict__ Qb,
                                                      const u16* __restrict__ Kb,
                                                      const u16* __restrict__ Vtb,
                                                      u16* __restrict__ Yb) {
  // [stream][buf][K|V][32 rows * 64 u16], rows seg-swizzled (slot s holds seg s^(row&7))
  __shared__ u16 SMEM[2][2][2][2048];
  int bh = blockIdx.y;
  int b = bh >> 4, hh = bh & 15;
  int tid = threadIdx.x, lane = tid & 63, wv = tid >> 6;
  int wq = wv & 1, wk = wv >> 1;
  int c5 = lane & 31, h = lane >> 5;
  int q0 = blockIdx.x * 64 + wq * 32;
  const u16* Qh = Qb + (size_t)bh * 2048 * 64;
  const u16* Kh = Kb + (size_t)bh * 2048 * 64;
  const u16* Vh = Vtb + (size_t)bh * 64 * 2048;

  // Q in registers: B-operand frags, qf[dc] = Q[q=c5][dc*16 + h*8 .. +7]
  const u16* Qrow = Qh + (size_t)(q0 + c5) * 64;
  bf16x8 qf[4];
#pragma unroll
  for (int dc = 0; dc < 4; ++dc)
    qf[dc] = *(const bf16x8*)&Qrow[dc * 16 + h * 8];

  f32x16 acc0 = {}, acc1 = {};  // acc0[j]=Y[q=(j&3)+8*(j>>2)+4h][d=c5], acc1: d=32+c5
  float mx = -1e30f, ls = 0.f;

  // hoisted per-thread staging assignment (4 parts), advance by constant stride
  const u16* gsrc[4];
  int gstep[4];
  u16* ld0[4];
  u16* ld1[4];
#pragma unroll
  for (int part = 0; part < 4; ++part) {
    int ci = part * 256 + tid;   // 0..1023 slots of 16B
    int st = ci >> 9;            // stream (kv half)
    int rem = ci & 511;
    int kv = rem >> 8;           // 0=K, 1=V
    int slot = rem & 255;
    int row = slot >> 3, seg = slot & 7;
    int sseg = seg ^ (row & 7);
    int t0 = st * 1024;
    if (kv == 0) {
      gsrc[part] = Kh + (size_t)(t0 + row) * 64 + sseg * 8;
      gstep[part] = 32 * 64;
    } else {
      int dh = sseg >> 2, ksl = sseg & 3;
      gsrc[part] = Vh + (size_t)(dh * 32 + row) * 2048 + t0 + ksl * 8;
      gstep[part] = 32;
    }
    ld0[part] = &SMEM[st][0][kv][slot * 8];
    ld1[part] = &SMEM[st][1][kv][slot * 8];
  }
  auto stagepair = [&](int buf) {
#pragma unroll
    for (int part = 0; part < 4; ++part) {
      gll16(gsrc[part], buf ? ld1[part] : ld0[part]);
      gsrc[part] += gstep[part];
    }
  };

  stagepair(0);
  int cur = 0;
  for (int it = 0; it < 32; ++it) {
    __syncthreads();  // buf[cur] staged (barrier drains vmcnt); prior reads done
    if (it + 1 < 32) stagepair(cur ^ 1);
    const u16* Kt = &SMEM[wk][cur][0][0];
    const u16* Vt = &SMEM[wk][cur][1][0];

    // ---- S^T = K x Q (one 32x32 tile, K-contraction d=64) ----
    f32x16 s0 = {};
    __builtin_amdgcn_s_setprio(1);
#pragma unroll
    for (int dc = 0; dc < 4; ++dc) {
      bf16x8 kf = *(const bf16x8*)&Kt[c5 * 64 + (((dc * 2 + h) ^ (c5 & 7)) * 8)];
      s0 = mfma32(kf, qf[dc], s0);
    }
    __builtin_amdgcn_s_setprio(0);

    // ---- softmax, in-register (log2 domain), defer-max THR=8 ----
    float t4[4];
#pragma unroll
    for (int i = 0; i < 4; ++i)
      t4[i] = fmaxf(fmaxf(s0[i], s0[i + 4]), fmaxf(s0[i + 8], s0[i + 12]));
    float mtile = fmaxf(fmaxf(t4[0], t4[1]), fmaxf(t4[2], t4[3]));
    mtile = fmaxf(mtile, __shfl_xor(mtile, 32));  // combine h halves
    if (!__all(mtile - mx <= 8.0f)) {
      float mn = fmaxf(mx, mtile);
      float corr = exp2f(mx - mn);
      ls *= corr;
      mx = mn;
#pragma unroll
      for (int j = 0; j < 16; ++j) {
        float cb = __shfl(corr, (j & 3) + 8 * (j >> 2) + 4 * h, 64);
        acc0[j] *= cb;
        acc1[j] *= cb;
      }
    }
#pragma unroll
    for (int j = 0; j < 16; ++j) s0[j] = exp2f(s0[j] - mx);
#pragma unroll
    for (int i = 0; i < 4; ++i)
      t4[i] = (s0[i] + s0[i + 4]) + (s0[i + 8] + s0[i + 12]);
    ls += (t4[0] + t4[1]) + (t4[2] + t4[3]);  // per-lane partial (h-split), merged later

    // pack P to bf16: w0[q2*2+pp] = (p[4q2+2pp], p[4q2+2pp+1])
    unsigned w0[8];
#pragma unroll
    for (int q2 = 0; q2 < 4; ++q2)
#pragma unroll
      for (int pp = 0; pp < 2; ++pp)
        w0[q2 * 2 + pp] = cvtpk(s0[q2 * 4 + 2 * pp], s0[q2 * 4 + 2 * pp + 1]);

    // ---- Y += P V ----
    __builtin_amdgcn_s_setprio(1);
#pragma unroll
    for (int ks2 = 0; ks2 < 2; ++ks2) {
      unsigned a0 = w0[4 * ks2 + 0], b0 = w0[4 * ks2 + 2];
      unsigned a1 = w0[4 * ks2 + 1], b1 = w0[4 * ks2 + 3];
      plswap(a0, b0);
      plswap(a1, b1);
      u32x4 aw = {a0, a1, b0, b1};
      bf16x8 af = __builtin_bit_cast(bf16x8, aw);
      bf16x8 vf0 = *(const bf16x8*)&Vt[c5 * 64 + (((ks2 * 2 + h) ^ (c5 & 7)) * 8)];
      bf16x8 vf1 = *(const bf16x8*)&Vt[c5 * 64 + (((4 + ks2 * 2 + h) ^ (c5 & 7)) * 8)];
      acc0 = mfma32(af, vf0, acc0);
      acc1 = mfma32(af, vf1, acc1);
    }
    __builtin_amdgcn_s_setprio(0);
    cur ^= 1;
  }

  // ---- merge the two KV halves (flash combine), then store ----
  float* MG = (float*)&SMEM[0][0][0][0];  // 32 KB free after last barrier
  int gi = wq * 64 + lane;
  __syncthreads();
  if (wk == 1) {
    MG[gi] = mx;
    MG[128 + gi] = ls;
#pragma unroll
    for (int j = 0; j < 16; ++j) {
      MG[256 + gi * 33 + j] = acc0[j];
      MG[256 + gi * 33 + 16 + j] = acc1[j];
    }
  }
  __syncthreads();
  if (wk == 0) {
    float mxB = MG[gi], lsB = MG[128 + gi];
    float m = fmaxf(mx, mxB);
    float cA = exp2f(mx - m), cB = exp2f(mxB - m);
    float l2 = ls * cA + lsB * cB;
    l2 += __shfl_xor(l2, 32);  // combine h halves
    float inv = 1.0f / l2;
#pragma unroll
    for (int j = 0; j < 16; ++j) {
      int q = (j & 3) + 8 * (j >> 2) + 4 * h;
      float cAq = __shfl(cA, q, 64);
      float cBq = __shfl(cB, q, 64);
      float ibq = __shfl(inv, q, 64);
      float y0 = (acc0[j] * cAq + MG[256 + gi * 33 + j] * cBq) * ibq;
      float y1 = (acc1[j] * cAq + MG[256 + gi * 33 + 16 + j] * cBq) * ibq;
      int trow = q0 + q;
      size_t base = ((size_t)b * 2048 + trow) * 1024 + hh * 64;
      Yb[base + c5] = f2b(y0);
      Yb[base + 32 + c5] = f2b(y1);
    }
  }
}

// ---------------- GEMM3: out = y @ w_proj^T + b_proj (fp32 out) ----------------
__global__ __launch_bounds__(256) void gemm_proj(const u16* __restrict__ A,
                                                 const u16* __restrict__ W,
                                                 const float* __restrict__ bias,
                                                 float* __restrict__ out) {
  __shared__ u16 As[2][128 * 64];
  __shared__ u16 Bs[2][128 * 64];
  const int K = 1024;
  int bn = blockIdx.x, bm = blockIdx.y;
  int tid = threadIdx.x, lane = tid & 63, w = tid >> 6;
  int wm = w >> 1, wn = w & 1, g = lane >> 4, c = lane & 15;
  f32x4 acc[4][4] = {};
  const u16* Arow = A + (size_t)(bm * 128) * K;
  const u16* Wrow = W + (size_t)(bn * 128) * K;

  auto stage = [&](int buf, int k0) {
#pragma unroll
    for (int rr = 0; rr < 4; ++rr) {
      int ci = rr * 256 + tid;
      int row = ci >> 3, sseg = (ci & 7) ^ (row & 7);
      gll16(Arow + (size_t)row * K + k0 + sseg * 8, &As[buf][ci * 8]);
    }
#pragma unroll
    for (int rr = 0; rr < 4; ++rr) {
      int ci = rr * 256 + tid;
      int row = ci >> 3, sseg = (ci & 7) ^ (row & 7);
      gll16(Wrow + (size_t)row * K + k0 + sseg * 8, &Bs[buf][ci * 8]);
    }
  };

  stage(0, 0);
  int cur = 0;
  for (int k0 = 0; k0 < K; k0 += 64) {
    __syncthreads();
    if (k0 + 64 < K) stage(cur ^ 1, k0 + 64);
#pragma unroll
    for (int kk = 0; kk < 2; ++kk) {
      int q = kk * 4 + g;
      bf16x8 af[4], bfr[4];
#pragma unroll
      for (int mi = 0; mi < 4; ++mi) {
        int row = wm * 64 + mi * 16 + c;
        af[mi] = *(const bf16x8*)&As[cur][row * 64 + ((q ^ (c & 7)) * 8)];
      }
#pragma unroll
      for (int ni = 0; ni < 4; ++ni) {
        int row = wn * 64 + ni * 16 + c;
        bfr[ni] = *(const bf16x8*)&Bs[cur][row * 64 + ((q ^ (c & 7)) * 8)];
      }
#pragma unroll
      for (int mi = 0; mi < 4; ++mi)
#pragma unroll
        for (int ni = 0; ni < 4; ++ni)
          acc[mi][ni] = mfma16(af[mi], bfr[ni], acc[mi][ni]);
    }
    cur ^= 1;
  }
#pragma unroll
  for (int mi = 0; mi < 4; ++mi)
#pragma unroll
    for (int ni = 0; ni < 4; ++ni)
#pragma unroll
      for (int r = 0; r < 4; ++r) {
        int row = bm * 128 + wm * 64 + mi * 16 + g * 4 + r;
        int col = bn * 128 + wn * 64 + ni * 16 + c;
        out[(size_t)row * 1024 + col] = acc[mi][ni][r] + bias[col];
      }
}

extern "C" void kernel_launch(void* const* d_in, const int* in_sizes, int n_in,
                              void* d_out, int out_size, void* d_ws, size_t ws_size,
                              hipStream_t stream) {
  const float* x      = (const float*)d_in[0];  // [2,2048,1024]
  const float* w_attn = (const float*)d_in[1];  // [3072,1024]
  const float* b_attn = (const float*)d_in[2];  // [3072]
  const float* w_proj = (const float*)d_in[3];  // [1024,1024]
  const float* b_proj = (const float*)d_in[4];  // [1024]
  float* out = (float*)d_out;

  u16* ws = (u16*)d_ws;
  const size_t XB  = 0;                 // 4096*1024
  const size_t WAB = XB + 4194304;      // 3072*1024
  const size_t WPB = WAB + 3145728;     // 1024*1024
  const size_t QB  = WPB + 1048576;     // 2*16*2048*64
  const size_t KB  = QB + 4194304;
  const size_t VTB = KB + 4194304;      // [bh][64][2048]
  const size_t YB  = VTB + 4194304;     // 4096*1024

  cvt3<<<8192, 256, 0, stream>>>(x, w_attn, w_proj, ws + XB, ws + WAB, ws + WPB);

  gemm_qkv<<<192, 512, 0, stream>>>(ws + XB, ws + WAB, b_attn,
                                    ws + QB, ws + KB, ws + VTB);

  attn_kernel<<<dim3(32, 32), 256, 0, stream>>>(ws + QB, ws + KB, ws + VTB, ws + YB);

  gemm_proj<<<dim3(8, 32), 256, 0, stream>>>(ws + YB, ws + WPB, b_proj, out);
}

// Round 8
// 142.364 us; speedup vs baseline: 1.3433x; 1.0235x over previous
//
#include <hip/hip_runtime.h>
#include <hip/hip_bf16.h>

typedef unsigned short u16;
typedef __bf16 bf16x8 __attribute__((ext_vector_type(8)));
typedef float f32x4 __attribute__((ext_vector_type(4)));
typedef float f32x16 __attribute__((ext_vector_type(16)));
typedef unsigned u32x4 __attribute__((ext_vector_type(4)));

// B=2, T=2048, C=1024, H=16, hd=64. scale = 1/32; log2(e)/32 folded into Q.
#define QSCALE 0.045084220027780106f

__device__ __forceinline__ u16 f2b(float f) {
  unsigned x = __float_as_uint(f);
  unsigned r = (x + 0x7fffu + ((x >> 16) & 1u)) >> 16;  // RNE
  return (u16)r;
}

__device__ __forceinline__ void gll16(const void* g, void* l) {
  __builtin_amdgcn_global_load_lds((const __attribute__((address_space(1))) void*)g,
                                   (__attribute__((address_space(3))) void*)l, 16, 0, 0);
}

__device__ __forceinline__ f32x4 mfma16(bf16x8 a, bf16x8 b, f32x4 c) {
  return __builtin_amdgcn_mfma_f32_16x16x32_bf16(a, b, c, 0, 0, 0);
}
__device__ __forceinline__ f32x16 mfma32(bf16x8 a, bf16x8 b, f32x16 c) {
  return __builtin_amdgcn_mfma_f32_32x32x16_bf16(a, b, c, 0, 0, 0);
}

// v_permlane32_swap_b32 a,b : a' = {a_lo, b_lo}, b' = {a_hi, b_hi}
// ONLY safe with operands holding distinct values (identical values may be
// register-coalesced -> v_permlane32_swap_b32 v, v == half-swap, wrong).
__device__ __forceinline__ void plswap(unsigned& a, unsigned& b) {
  asm volatile("v_permlane32_swap_b32 %0, %1" : "+v"(a), "+v"(b));
}
__device__ __forceinline__ unsigned cvtpk(float lo, float hi) {
  unsigned r;
  asm("v_cvt_pk_bf16_f32 %0, %1, %2" : "=v"(r) : "v"(lo), "v"(hi));
  return r;
}

// ---------------- fp32 -> bf16 convert (all three tensors, one launch) ----------------
__global__ __launch_bounds__(256) void cvt3(const float* __restrict__ x,
                                            const float* __restrict__ wa,
                                            const float* __restrict__ wp,
                                            u16* __restrict__ dx,
                                            u16* __restrict__ dwa,
                                            u16* __restrict__ dwp) {
  const int N1 = 4194304, N2 = 3145728;
  int i = (blockIdx.x * 256 + threadIdx.x) * 4;
  const float* s;
  u16* d;
  int off;
  if (i < N1) { s = x; d = dx; off = i; }
  else if (i < N1 + N2) { s = wa; d = dwa; off = i - N1; }
  else { s = wp; d = dwp; off = i - N1 - N2; }
  float4 v = *(const float4*)(s + off);
  ushort4 o;
  o.x = f2b(v.x); o.y = f2b(v.y); o.z = f2b(v.z); o.w = f2b(v.w);
  *(ushort4*)(d + off) = o;
}

// ---------------- GEMM1: qkv = x @ w_attn^T + b_attn, scatter to Q/K/Vt ----------------
// 256x256 tile, 8 waves (2M x 4N), BK=64, double-buffered single-barrier loop.
// LDS rows seg-XOR-swizzled. Epilogue: Q/K direct (32B full sectors); V routed
// through a 64KB LDS transpose (VT aliases As) -> b128 contiguous Vt stores.
__global__ __launch_bounds__(512) void gemm_qkv(const u16* __restrict__ A,
                                                const u16* __restrict__ W,
                                                const float* __restrict__ bias,
                                                u16* __restrict__ Qb,
                                                u16* __restrict__ Kb,
                                                u16* __restrict__ Vtb) {
  __shared__ u16 As[2][256 * 64];
  __shared__ u16 Bs[2][256 * 64];
  const int K = 1024;
  int o = blockIdx.x;             // 0..191
  int xcd = o & 7, li = o >> 3;   // li 0..23
  int bm = (xcd >> 1) * 4 + li / 6;   // 0..15
  int bn = (xcd & 1) * 6 + li % 6;    // 0..11
  int tid = threadIdx.x, lane = tid & 63, w = tid >> 6;
  int wm = w >> 2, wn = w & 3, g = lane >> 4, c = lane & 15;
  f32x4 acc[8][4] = {};
  const u16* Arow = A + (size_t)(bm * 256) * K;
  const u16* Wrow = W + (size_t)(bn * 256) * K;

  // hoisted staging addresses: 4 slots each for A and B per thread
  const u16* asrc[4];
  const u16* bsrc[4];
  int sdst[4];
#pragma unroll
  for (int rr = 0; rr < 4; ++rr) {
    int ci = rr * 512 + tid;  // 0..2047 16B-slots
    int row = ci >> 3, sseg = (ci & 7) ^ (row & 7);
    asrc[rr] = Arow + (size_t)row * K + sseg * 8;
    bsrc[rr] = Wrow + (size_t)row * K + sseg * 8;
    sdst[rr] = ci * 8;
  }
  auto stage = [&](int buf) {
#pragma unroll
    for (int rr = 0; rr < 4; ++rr) gll16(asrc[rr], &As[buf][sdst[rr]]);
#pragma unroll
    for (int rr = 0; rr < 4; ++rr) gll16(bsrc[rr], &Bs[buf][sdst[rr]]);
#pragma unroll
    for (int rr = 0; rr < 4; ++rr) { asrc[rr] += 64; bsrc[rr] += 64; }
  };

  stage(0);
  int cur = 0;
  for (int k0 = 0; k0 < K; k0 += 64) {
    __syncthreads();  // drains vmcnt: buf[cur] staged; prior LDS reads done
    if (k0 + 64 < K) stage(cur ^ 1);
#pragma unroll
    for (int kk = 0; kk < 2; ++kk) {
      bf16x8 af[8], bfr[4];
#pragma unroll
      for (int mi = 0; mi < 8; ++mi) {
        int row = wm * 128 + mi * 16 + c;
        af[mi] = *(const bf16x8*)&As[cur][row * 64 + (((kk * 4 + g) ^ (row & 7)) * 8)];
      }
#pragma unroll
      for (int ni = 0; ni < 4; ++ni) {
        int row = wn * 64 + ni * 16 + c;
        bfr[ni] = *(const bf16x8*)&Bs[cur][row * 64 + (((kk * 4 + g) ^ (row & 7)) * 8)];
      }
      __builtin_amdgcn_s_setprio(1);
#pragma unroll
      for (int mi = 0; mi < 8; ++mi)
#pragma unroll
        for (int ni = 0; ni < 4; ++ni)
          acc[mi][ni] = mfma16(af[mi], bfr[ni], acc[mi][ni]);
      __builtin_amdgcn_s_setprio(0);
    }
    cur ^= 1;
  }

  // ---------------- epilogue ----------------
  __syncthreads();  // all LDS reads of As/Bs done; VT may alias As
  u16* VT = &As[0][0];  // VT[vcl][256 trow], 16B-slot swizzled, up to 128x256x2B=64KB
  int bb = bm >> 3;                // batch (rows 256-aligned, 2048 | batch boundary)
  int tbase = (bm & 7) << 8;       // t of trow 0
  int m = (bn * 64) % 192;         // block col-start mod 192 (0/64/128)
  int base_h = (bn * 256) / 192;

  // per-ni column classification (wave-uniform: 16-col chunks never straddle 64-boundaries)
  int cls[4], qkoff[4], vb[4], vx[4];
  float bi[4];
#pragma unroll
  for (int ni = 0; ni < 4; ++ni) {
    int cl = wn * 64 + ni * 16 + c;
    bi[ni] = bias[bn * 256 + cl];
    int q = cl + m;
    int rh = q >= 192;
    int j = q - rh * 192;
    int bh = bb * 16 + base_h + rh;
    if (j < 64) { cls[ni] = 0; qkoff[ni] = bh * 131072 + j; }
    else if (j < 128) { cls[ni] = 1; qkoff[ni] = bh * 131072 + (j - 64); }
    else { cls[ni] = 2; int vcl = rh * 64 + (j - 128); vb[ni] = vcl * 256; vx[ni] = (vcl & 15) << 3; }
  }
#pragma unroll
  for (int mi = 0; mi < 8; ++mi)
#pragma unroll
    for (int r = 0; r < 4; ++r) {
      int trow = wm * 128 + mi * 16 + g * 4 + r;
      int t = tbase + trow;
#pragma unroll
      for (int ni = 0; ni < 4; ++ni) {
        float v = acc[mi][ni][r] + bi[ni];
        if (cls[ni] == 0) Qb[(size_t)qkoff[ni] + t * 64] = f2b(v * QSCALE);
        else if (cls[ni] == 1) Kb[(size_t)qkoff[ni] + t * 64] = f2b(v);
        else VT[vb[ni] + (trow ^ vx[ni])] = f2b(v);
      }
    }
  __syncthreads();
  // phase B: V transpose store, b128 contiguous along t
  int nV = (m == 128) ? 128 : 64;
  for (int id = tid; id < nV * 32; id += 512) {
    int vcl = id >> 5, tc = id & 31;
    bf16x8 vv = *(const bf16x8*)&VT[vcl * 256 + ((tc * 8) ^ ((vcl & 15) << 3))];
    int rh = vcl >> 6, d = vcl & 63;
    size_t dst = ((size_t)(bb * 16 + base_h + rh) * 64 + d) * 2048 + tbase + tc * 8;
    *(bf16x8*)&Vtb[dst] = vv;
  }
}

// ---------------- Flash attention, 32x32 swapped-QK^T + split-K ----------------
// grid: (T/64, B*H). 4 waves/block: wave = (wq, wk); wq picks q rows
// [wq*32,+32); wk picks KV half. Staging addresses hoisted (fixed per-thread
// src pointer + constant stride). Merge accumulator stride padded to 33 f32.
__global__ __launch_bounds__(256, 4) void attn_kernel(const u16* __restrict__ Qb,
                                                      const u16* __restrict__ Kb,
                                                      const u16* __restrict__ Vtb,
                                                      u16* __restrict__ Yb) {
  // [stream][buf][K|V][32 rows * 64 u16], rows seg-swizzled (slot s holds seg s^(row&7))
  __shared__ u16 SMEM[2][2][2][2048];
  int bh = blockIdx.y;
  int b = bh >> 4, hh = bh & 15;
  int tid = threadIdx.x, lane = tid & 63, wv = tid >> 6;
  int wq = wv & 1, wk = wv >> 1;
  int c5 = lane & 31, h = lane >> 5;
  int q0 = blockIdx.x * 64 + wq * 32;
  const u16* Qh = Qb + (size_t)bh * 2048 * 64;
  const u16* Kh = Kb + (size_t)bh * 2048 * 64;
  const u16* Vh = Vtb + (size_t)bh * 64 * 2048;

  // Q in registers: B-operand frags, qf[dc] = Q[q=c5][dc*16 + h*8 .. +7]
  const u16* Qrow = Qh + (size_t)(q0 + c5) * 64;
  bf16x8 qf[4];
#pragma unroll
  for (int dc = 0; dc < 4; ++dc)
    qf[dc] = *(const bf16x8*)&Qrow[dc * 16 + h * 8];

  f32x16 acc0 = {}, acc1 = {};  // acc0[j]=Y[q=(j&3)+8*(j>>2)+4h][d=c5], acc1: d=32+c5
  float mx = -1e30f, ls = 0.f;

  // hoisted per-thread staging assignment (4 parts), advance by constant stride
  const u16* gsrc[4];
  int gstep[4];
  u16* ld0[4];
  u16* ld1[4];
#pragma unroll
  for (int part = 0; part < 4; ++part) {
    int ci = part * 256 + tid;   // 0..1023 slots of 16B
    int st = ci >> 9;            // stream (kv half)
    int rem = ci & 511;
    int kv = rem >> 8;           // 0=K, 1=V
    int slot = rem & 255;
    int row = slot >> 3, seg = slot & 7;
    int sseg = seg ^ (row & 7);
    int t0 = st * 1024;
    if (kv == 0) {
      gsrc[part] = Kh + (size_t)(t0 + row) * 64 + sseg * 8;
      gstep[part] = 32 * 64;
    } else {
      int dh = sseg >> 2, ksl = sseg & 3;
      gsrc[part] = Vh + (size_t)(dh * 32 + row) * 2048 + t0 + ksl * 8;
      gstep[part] = 32;
    }
    ld0[part] = &SMEM[st][0][kv][slot * 8];
    ld1[part] = &SMEM[st][1][kv][slot * 8];
  }
  auto stagepair = [&](int buf) {
#pragma unroll
    for (int part = 0; part < 4; ++part) {
      gll16(gsrc[part], buf ? ld1[part] : ld0[part]);
      gsrc[part] += gstep[part];
    }
  };

  stagepair(0);
  int cur = 0;
  for (int it = 0; it < 32; ++it) {
    __syncthreads();  // buf[cur] staged (barrier drains vmcnt); prior reads done
    if (it + 1 < 32) stagepair(cur ^ 1);
    const u16* Kt = &SMEM[wk][cur][0][0];
    const u16* Vt = &SMEM[wk][cur][1][0];

    // ---- S^T = K x Q (one 32x32 tile, K-contraction d=64) ----
    f32x16 s0 = {};
    __builtin_amdgcn_s_setprio(1);
#pragma unroll
    for (int dc = 0; dc < 4; ++dc) {
      bf16x8 kf = *(const bf16x8*)&Kt[c5 * 64 + (((dc * 2 + h) ^ (c5 & 7)) * 8)];
      s0 = mfma32(kf, qf[dc], s0);
    }
    __builtin_amdgcn_s_setprio(0);

    // ---- softmax, in-register (log2 domain), defer-max THR=8 ----
    float t4[4];
#pragma unroll
    for (int i = 0; i < 4; ++i)
      t4[i] = fmaxf(fmaxf(s0[i], s0[i + 4]), fmaxf(s0[i + 8], s0[i + 12]));
    float mtile = fmaxf(fmaxf(t4[0], t4[1]), fmaxf(t4[2], t4[3]));
    mtile = fmaxf(mtile, __shfl_xor(mtile, 32));  // combine h halves
    if (!__all(mtile - mx <= 8.0f)) {
      float mn = fmaxf(mx, mtile);
      float corr = exp2f(mx - mn);
      ls *= corr;
      mx = mn;
#pragma unroll
      for (int j = 0; j < 16; ++j) {
        float cb = __shfl(corr, (j & 3) + 8 * (j >> 2) + 4 * h, 64);
        acc0[j] *= cb;
        acc1[j] *= cb;
      }
    }
#pragma unroll
    for (int j = 0; j < 16; ++j) s0[j] = exp2f(s0[j] - mx);
#pragma unroll
    for (int i = 0; i < 4; ++i)
      t4[i] = (s0[i] + s0[i + 4]) + (s0[i + 8] + s0[i + 12]);
    ls += (t4[0] + t4[1]) + (t4[2] + t4[3]);  // per-lane partial (h-split), merged later

    // pack P to bf16: w0[q2*2+pp] = (p[4q2+2pp], p[4q2+2pp+1])
    unsigned w0[8];
#pragma unroll
    for (int q2 = 0; q2 < 4; ++q2)
#pragma unroll
      for (int pp = 0; pp < 2; ++pp)
        w0[q2 * 2 + pp] = cvtpk(s0[q2 * 4 + 2 * pp], s0[q2 * 4 + 2 * pp + 1]);

    // ---- Y += P V ----
    __builtin_amdgcn_s_setprio(1);
#pragma unroll
    for (int ks2 = 0; ks2 < 2; ++ks2) {
      unsigned a0 = w0[4 * ks2 + 0], b0 = w0[4 * ks2 + 2];
      unsigned a1 = w0[4 * ks2 + 1], b1 = w0[4 * ks2 + 3];
      plswap(a0, b0);
      plswap(a1, b1);
      u32x4 aw = {a0, a1, b0, b1};
      bf16x8 af = __builtin_bit_cast(bf16x8, aw);
      bf16x8 vf0 = *(const bf16x8*)&Vt[c5 * 64 + (((ks2 * 2 + h) ^ (c5 & 7)) * 8)];
      bf16x8 vf1 = *(const bf16x8*)&Vt[c5 * 64 + (((4 + ks2 * 2 + h) ^ (c5 & 7)) * 8)];
      acc0 = mfma32(af, vf0, acc0);
      acc1 = mfma32(af, vf1, acc1);
    }
    __builtin_amdgcn_s_setprio(0);
    cur ^= 1;
  }

  // ---- merge the two KV halves (flash combine), then store ----
  float* MG = (float*)&SMEM[0][0][0][0];  // 32 KB free after last barrier
  int gi = wq * 64 + lane;
  __syncthreads();
  if (wk == 1) {
    MG[gi] = mx;
    MG[128 + gi] = ls;
#pragma unroll
    for (int j = 0; j < 16; ++j) {
      MG[256 + gi * 33 + j] = acc0[j];
      MG[256 + gi * 33 + 16 + j] = acc1[j];
    }
  }
  __syncthreads();
  if (wk == 0) {
    float mxB = MG[gi], lsB = MG[128 + gi];
    float m = fmaxf(mx, mxB);
    float cA = exp2f(mx - m), cB = exp2f(mxB - m);
    float l2 = ls * cA + lsB * cB;
    l2 += __shfl_xor(l2, 32);  // combine h halves
    float inv = 1.0f / l2;
#pragma unroll
    for (int j = 0; j < 16; ++j) {
      int q = (j & 3) + 8 * (j >> 2) + 4 * h;
      float cAq = __shfl(cA, q, 64);
      float cBq = __shfl(cB, q, 64);
      float ibq = __shfl(inv, q, 64);
      float y0 = (acc0[j] * cAq + MG[256 + gi * 33 + j] * cBq) * ibq;
      float y1 = (acc1[j] * cAq + MG[256 + gi * 33 + 16 + j] * cBq) * ibq;
      int trow = q0 + q;
      size_t base = ((size_t)b * 2048 + trow) * 1024 + hh * 64;
      Yb[base + c5] = f2b(y0);
      Yb[base + 32 + c5] = f2b(y1);
    }
  }
}

// ---------------- GEMM3: out = y @ w_proj^T + b_proj (fp32 out) ----------------
__global__ __launch_bounds__(256) void gemm_proj(const u16* __restrict__ A,
                                                 const u16* __restrict__ W,
                                                 const float* __restrict__ bias,
                                                 float* __restrict__ out) {
  __shared__ u16 As[2][128 * 64];
  __shared__ u16 Bs[2][128 * 64];
  const int K = 1024;
  int bn = blockIdx.x, bm = blockIdx.y;
  int tid = threadIdx.x, lane = tid & 63, w = tid >> 6;
  int wm = w >> 1, wn = w & 1, g = lane >> 4, c = lane & 15;
  f32x4 acc[4][4] = {};
  const u16* Arow = A + (size_t)(bm * 128) * K;
  const u16* Wrow = W + (size_t)(bn * 128) * K;

  auto stage = [&](int buf, int k0) {
#pragma unroll
    for (int rr = 0; rr < 4; ++rr) {
      int ci = rr * 256 + tid;
      int row = ci >> 3, sseg = (ci & 7) ^ (row & 7);
      gll16(Arow + (size_t)row * K + k0 + sseg * 8, &As[buf][ci * 8]);
    }
#pragma unroll
    for (int rr = 0; rr < 4; ++rr) {
      int ci = rr * 256 + tid;
      int row = ci >> 3, sseg = (ci & 7) ^ (row & 7);
      gll16(Wrow + (size_t)row * K + k0 + sseg * 8, &Bs[buf][ci * 8]);
    }
  };

  stage(0, 0);
  int cur = 0;
  for (int k0 = 0; k0 < K; k0 += 64) {
    __syncthreads();
    if (k0 + 64 < K) stage(cur ^ 1, k0 + 64);
#pragma unroll
    for (int kk = 0; kk < 2; ++kk) {
      int q = kk * 4 + g;
      bf16x8 af[4], bfr[4];
#pragma unroll
      for (int mi = 0; mi < 4; ++mi) {
        int row = wm * 64 + mi * 16 + c;
        af[mi] = *(const bf16x8*)&As[cur][row * 64 + ((q ^ (c & 7)) * 8)];
      }
#pragma unroll
      for (int ni = 0; ni < 4; ++ni) {
        int row = wn * 64 + ni * 16 + c;
        bfr[ni] = *(const bf16x8*)&Bs[cur][row * 64 + ((q ^ (c & 7)) * 8)];
      }
#pragma unroll
      for (int mi = 0; mi < 4; ++mi)
#pragma unroll
        for (int ni = 0; ni < 4; ++ni)
          acc[mi][ni] = mfma16(af[mi], bfr[ni], acc[mi][ni]);
    }
    cur ^= 1;
  }
#pragma unroll
  for (int mi = 0; mi < 4; ++mi)
#pragma unroll
    for (int ni = 0; ni < 4; ++ni)
#pragma unroll
      for (int r = 0; r < 4; ++r) {
        int row = bm * 128 + wm * 64 + mi * 16 + g * 4 + r;
        int col = bn * 128 + wn * 64 + ni * 16 + c;
        out[(size_t)row * 1024 + col] = acc[mi][ni][r] + bias[col];
      }
}

extern "C" void kernel_launch(void* const* d_in, const int* in_sizes, int n_in,
                              void* d_out, int out_size, void* d_ws, size_t ws_size,
                              hipStream_t stream) {
  const float* x      = (const float*)d_in[0];  // [2,2048,1024]
  const float* w_attn = (const float*)d_in[1];  // [3072,1024]
  const float* b_attn = (const float*)d_in[2];  // [3072]
  const float* w_proj = (const float*)d_in[3];  // [1024,1024]
  const float* b_proj = (const float*)d_in[4];  // [1024]
  float* out = (float*)d_out;

  u16* ws = (u16*)d_ws;
  const size_t XB  = 0;                 // 4096*1024
  const size_t WAB = XB + 4194304;      // 3072*1024
  const size_t WPB = WAB + 3145728;     // 1024*1024
  const size_t QB  = WPB + 1048576;     // 2*16*2048*64
  const size_t KB  = QB + 4194304;
  const size_t VTB = KB + 4194304;      // [bh][64][2048]
  const size_t YB  = VTB + 4194304;     // 4096*1024

  cvt3<<<8192, 256, 0, stream>>>(x, w_attn, w_proj, ws + XB, ws + WAB, ws + WPB);

  gemm_qkv<<<192, 512, 0, stream>>>(ws + XB, ws + WAB, b_attn,
                                    ws + QB, ws + KB, ws + VTB);

  attn_kernel<<<dim3(32, 32), 256, 0, stream>>>(ws + QB, ws + KB, ws + VTB, ws + YB);

  gemm_proj<<<dim3(8, 32), 256, 0, stream>>>(ws + YB, ws + WPB, b_proj, out);
}